// Round 1
// baseline (1322.934 us; speedup 1.0000x reference)
//
#include <hip/hip_runtime.h>
#include <math.h>

#define A_N     18525
#define B_N     2
#define NCLS    81
#define FG      80
#define TOPN    200
#define MAXOBJ  100
#define PROTO_N 136
#define OUT_N   544
#define COEF_N  32
#define FLATN   (FG*TOPN)      // 16000
#define MIN_SCORE 0.05f
#define NMS_T   0.5f
#define MASK_ELEMS ((size_t)B_N*MAXOBJ*OUT_N*OUT_N)  // 59,187,200

__device__ __forceinline__ void takeMax(float& bv, int& bi, float x, int i) {
    // value-desc, index-asc tie-break (matches stable argsort of negated scores).
    // NaN x is never taken (both comparisons false).
    if (x > bv || (x == bv && i < bi)) { bv = x; bi = i; }
}

// ---------------------------------------------------------------------------
// Kernel 1: softmax + anchor-valid mask + box decode.
// S[b][c][a] = anchor_valid ? softmax_fg_score : -1.0f   (class-major layout)
// boxes[b][a][4] = clipped (x1,y1,x2,y2)
// ---------------------------------------------------------------------------
__global__ __launch_bounds__(256) void k_decode(
    const float* __restrict__ cls, const float* __restrict__ boxd,
    const float* __restrict__ anchors,
    float* __restrict__ S, float* __restrict__ boxes)
{
    int idx = blockIdx.x * 256 + threadIdx.x;
    if (idx >= B_N * A_N) return;
    int b = idx / A_N, a = idx - b * A_N;
    const float* cl = cls + (size_t)idx * NCLS;

    float mx = cl[0];
    for (int i = 1; i < NCLS; ++i) mx = fmaxf(mx, cl[i]);
    float sum = 0.0f, mfg = -1e30f;
    for (int i = 0; i < NCLS; ++i) {
        float x = cl[i];
        sum += expf(x - mx);
        if (i > 0) mfg = fmaxf(mfg, x);
    }
    float inv = 1.0f / sum;
    int valid = (expf(mfg - mx) * inv) > MIN_SCORE;  // strict >

    for (int c = 0; c < FG; ++c) {
        float s = expf(cl[c + 1] - mx) * inv;
        S[((size_t)b * FG + c) * A_N + a] = valid ? s : -1.0f;
    }

    // box decode
    const float* an = anchors + (size_t)a * 4;
    const float* bd = boxd + (size_t)idx * 4;
    float aw = an[2], ah = an[3];
    float cx = an[0] + bd[0] * 0.1f * aw;
    float cy = an[1] + bd[1] * 0.1f * ah;
    float w  = aw * expf(bd[2] * 0.2f);
    float h  = ah * expf(bd[3] * 0.2f);
    float x1 = cx - w * 0.5f, y1 = cy - h * 0.5f;
    float x2 = x1 + w,        y2 = y1 + h;
    x1 = fminf(fmaxf(x1, 0.0f), 1.0f);
    y1 = fminf(fmaxf(y1, 0.0f), 1.0f);
    x2 = fminf(fmaxf(x2, 0.0f), 1.0f);
    y2 = fminf(fmaxf(y2, 0.0f), 1.0f);
    float* bo = boxes + (size_t)idx * 4;
    bo[0] = x1; bo[1] = y1; bo[2] = x2; bo[3] = y2;
}

// ---------------------------------------------------------------------------
// Kernel 2: per-(b,c) top-200 by iterative tie-aware argmax over LDS.
// ---------------------------------------------------------------------------
__global__ __launch_bounds__(512) void k_topk(
    const float* __restrict__ S, int* __restrict__ det_idx,
    float* __restrict__ det_score)
{
    extern __shared__ float v[];          // A_N floats (74100 B)
    __shared__ float wv[8];
    __shared__ int   wi[8];
    int bc = blockIdx.x;                  // b*FG + c
    int tid = threadIdx.x;
    const float* row = S + (size_t)bc * A_N;
    for (int i = tid; i < A_N; i += 512) v[i] = row[i];
    __syncthreads();

    for (int t = 0; t < TOPN; ++t) {
        float bv = -INFINITY; int bi = 0x7fffffff;
        for (int i = tid; i < A_N; i += 512) takeMax(bv, bi, v[i], i);
        for (int off = 32; off > 0; off >>= 1) {
            float ov = __shfl_down(bv, off);
            int   oi = __shfl_down(bi, off);
            takeMax(bv, bi, ov, oi);
        }
        int wid = tid >> 6;
        if ((tid & 63) == 0) { wv[wid] = bv; wi[wid] = bi; }
        __syncthreads();
        if (tid == 0) {
            float fv = wv[0]; int fi = wi[0];
            for (int w = 1; w < 8; ++w) takeMax(fv, fi, wv[w], wi[w]);
            det_idx[bc * TOPN + t]   = fi;
            det_score[bc * TOPN + t] = fv;
            v[fi] = -INFINITY;   // values are >= -1.0, so -inf never re-picked
        }
        __syncthreads();
    }
}

// ---------------------------------------------------------------------------
// Kernel 3: fast NMS per (b,c). flat[b][c*200+j] = keep ? score : -inf
// ---------------------------------------------------------------------------
__global__ __launch_bounds__(256) void k_nms(
    const float* __restrict__ boxes, const int* __restrict__ det_idx,
    const float* __restrict__ det_score, float* __restrict__ flat)
{
    __shared__ float bx1[TOPN], by1[TOPN], bx2[TOPN], by2[TOPN], ar[TOPN], sc[TOPN];
    __shared__ int dv[TOPN];
    int bc = blockIdx.x;
    int b = bc / FG, c = bc - b * FG;
    int tid = threadIdx.x;
    if (tid < TOPN) {
        int a = det_idx[bc * TOPN + tid];
        const float* bo = boxes + ((size_t)b * A_N + a) * 4;
        float x1 = bo[0], y1 = bo[1], x2 = bo[2], y2 = bo[3];
        bx1[tid] = x1; by1[tid] = y1; bx2[tid] = x2; by2[tid] = y2;
        ar[tid] = (x2 - x1) * (y2 - y1);
        float s = det_score[bc * TOPN + tid];
        sc[tid] = s;
        dv[tid] = (s > -0.5f) ? 1 : 0;   // invalid anchors stored as exactly -1.0
    }
    __syncthreads();
    if (tid < TOPN) {
        float x1 = bx1[tid], y1 = by1[tid], x2 = bx2[tid], y2 = by2[tid];
        float aj = ar[tid];
        bool sup = false;
        for (int i = 0; i < tid; ++i) {
            float iw = fmaxf(fminf(bx2[i], x2) - fmaxf(bx1[i], x1), 0.0f);
            float ih = fmaxf(fminf(by2[i], y2) - fmaxf(by1[i], y1), 0.0f);
            float inter = iw * ih;
            float iou = inter / (ar[i] + aj - inter);   // may be NaN (0/0)
            // reference: iou * det_valid[i] (NaN survives *0), keep = max <= T
            bool bad = dv[i] ? !(iou <= NMS_T) : isnan(iou);
            if (bad) sup = true;
        }
        bool keep = dv[tid] && !sup;
        flat[(size_t)b * FLATN + c * TOPN + tid] = keep ? sc[tid] : -INFINITY;
    }
}

// ---------------------------------------------------------------------------
// Kernel 4: global top-100 per batch + emit labels/scores/valid + crop bounds.
// Removed entries become NaN so the -inf (non-kept) group still orders by
// ascending flat index (stable-argsort semantics) without re-picking.
// ---------------------------------------------------------------------------
__global__ __launch_bounds__(1024) void k_top100(
    const float* __restrict__ flat, const int* __restrict__ det_idx,
    const float* __restrict__ boxes,
    float* __restrict__ lab, float* __restrict__ sco, float* __restrict__ va,
    int* __restrict__ sel_anchor, int* __restrict__ sel_valid,
    float* __restrict__ crop)
{
    __shared__ float v[FLATN];
    __shared__ float wv[16];
    __shared__ int   wi[16];
    int b = blockIdx.x;
    int tid = threadIdx.x;
    for (int i = tid; i < FLATN; i += 1024) v[i] = flat[(size_t)b * FLATN + i];
    __syncthreads();

    const float QNAN = __int_as_float(0x7fc00000);
    for (int k = 0; k < MAXOBJ; ++k) {
        float bv = -INFINITY; int bi = 0x7fffffff;
        for (int i = tid; i < FLATN; i += 1024) takeMax(bv, bi, v[i], i);
        for (int off = 32; off > 0; off >>= 1) {
            float ov = __shfl_down(bv, off);
            int   oi = __shfl_down(bi, off);
            takeMax(bv, bi, ov, oi);
        }
        int wid = tid >> 6;
        if ((tid & 63) == 0) { wv[wid] = bv; wi[wid] = bi; }
        __syncthreads();
        if (tid == 0) {
            float fv = wv[0]; int fi = wi[0];
            for (int w = 1; w < 16; ++w) takeMax(fv, fi, wv[w], wi[w]);
            int valid = (fv > -1e37f) ? 1 : 0;   // isfinite (scores are in (0,1])
            int c = fi / TOPN, t = fi - c * TOPN;
            int anchor = det_idx[((size_t)b * FG + c) * TOPN + t];
            lab[b * MAXOBJ + k] = valid ? (float)c : -1.0f;
            sco[b * MAXOBJ + k] = valid ? fv : 0.0f;
            va [b * MAXOBJ + k] = valid ? 1.0f : 0.0f;
            sel_anchor[b * MAXOBJ + k] = anchor;
            sel_valid [b * MAXOBJ + k] = valid;
            const float* bo = boxes + ((size_t)b * A_N + anchor) * 4;
            float xlo = fminf(bo[0], bo[2]), xhi = fmaxf(bo[0], bo[2]);
            float ylo = fminf(bo[1], bo[3]), yhi = fmaxf(bo[1], bo[3]);
            float* cr = crop + ((size_t)b * MAXOBJ + k) * 4;
            cr[0] = fmaxf(xlo * (float)PROTO_N - 1.0f, 0.0f);
            cr[1] = fminf(xhi * (float)PROTO_N + 1.0f, (float)PROTO_N);
            cr[2] = fmaxf(ylo * (float)PROTO_N - 1.0f, 0.0f);
            cr[3] = fminf(yhi * (float)PROTO_N + 1.0f, (float)PROTO_N);
            v[fi] = QNAN;
        }
        __syncthreads();
    }
}

// ---------------------------------------------------------------------------
// Kernel 5: proto @ coef^T -> sigmoid -> crop, at proto resolution.
// One block per (b, y) row. prow padded to stride 33 (bank-conflict-free).
// ---------------------------------------------------------------------------
__global__ __launch_bounds__(256) void k_mask(
    const float* __restrict__ proto, const float* __restrict__ coefs,
    const int* __restrict__ sel_anchor, const float* __restrict__ crop,
    float* __restrict__ maskbuf)
{
    __shared__ float prow[PROTO_N * 33];     // 136*33 floats
    __shared__ float cf[MAXOBJ * COEF_N];    // 100*32
    __shared__ float cb[MAXOBJ][4];
    int blk = blockIdx.x;
    int b = blk / PROTO_N, y = blk - b * PROTO_N;
    int tid = threadIdx.x;

    const float* pr = proto + ((size_t)(b * PROTO_N + y) * PROTO_N) * COEF_N;
    for (int i = tid; i < PROTO_N * COEF_N; i += 256) {
        int x = i >> 5, c = i & 31;
        prow[x * 33 + c] = pr[i];
    }
    for (int i = tid; i < MAXOBJ * COEF_N; i += 256) {
        int n = i >> 5, c = i & 31;
        cf[i] = coefs[((size_t)b * A_N + sel_anchor[b * MAXOBJ + n]) * COEF_N + c];
    }
    if (tid < MAXOBJ) {
        const float* cr = crop + ((size_t)b * MAXOBJ + tid) * 4;
        cb[tid][0] = cr[0]; cb[tid][1] = cr[1]; cb[tid][2] = cr[2]; cb[tid][3] = cr[3];
    }
    __syncthreads();

    float yf = (float)y;
    for (int idx = tid; idx < MAXOBJ * PROTO_N; idx += 256) {
        int n = idx / PROTO_N, x = idx - n * PROTO_N;
        const float* pp = prow + x * 33;
        const float* cp = cf + n * COEF_N;
        float d = 0.0f;
        #pragma unroll
        for (int c = 0; c < COEF_N; ++c) d = fmaf(pp[c], cp[c], d);
        float m = 1.0f / (1.0f + expf(-d));
        float xf = (float)x;
        bool keep = (xf >= cb[n][0]) && (xf < cb[n][1]) &&
                    (yf >= cb[n][2]) && (yf < cb[n][3]);
        maskbuf[(((size_t)b * MAXOBJ + n) * PROTO_N + y) * PROTO_N + x] = keep ? m : 0.0f;
    }
}

// ---------------------------------------------------------------------------
// Kernel 6: bilinear x4 upsample (half-pixel, clamped taps) + valid gate + >0.5
// One block per (b, n, 68-row output tile). Source rows staged in LDS.
// ---------------------------------------------------------------------------
__global__ __launch_bounds__(256) void k_resize(
    const float* __restrict__ maskbuf, const int* __restrict__ sel_valid,
    float* __restrict__ out)
{
    __shared__ float src[19 * PROTO_N];
    int blk = blockIdx.x;            // B*100*8
    int tile = blk & 7;
    int bn = blk >> 3;               // b*100+n
    int tid = threadIdx.x;

    int oy0 = tile * 68;
    float sy0 = (oy0 + 0.5f) * 0.25f - 0.5f;
    float sy1 = (oy0 + 67 + 0.5f) * 0.25f - 0.5f;
    int iy_lo = max((int)floorf(sy0), 0);
    int iy_hi = min((int)floorf(sy1) + 1, PROTO_N - 1);
    int nrows = iy_hi - iy_lo + 1;

    const float* mb = maskbuf + ((size_t)bn * PROTO_N + iy_lo) * PROTO_N;
    for (int i = tid; i < nrows * PROTO_N; i += 256) src[i] = mb[i];
    int val = sel_valid[bn];
    __syncthreads();

    for (int p = tid; p < 68 * OUT_N; p += 256) {
        int oy = oy0 + p / OUT_N;
        int ox = p - (p / OUT_N) * OUT_N;
        float sy = (oy + 0.5f) * 0.25f - 0.5f;
        int iy0 = (int)floorf(sy);
        float fy = sy - (float)iy0;
        int iyA = min(max(iy0, 0), PROTO_N - 1) - iy_lo;
        int iyB = min(max(iy0 + 1, 0), PROTO_N - 1) - iy_lo;
        float sx = (ox + 0.5f) * 0.25f - 0.5f;
        int ix0 = (int)floorf(sx);
        float fx = sx - (float)ix0;
        int ixA = min(max(ix0, 0), PROTO_N - 1);
        int ixB = min(max(ix0 + 1, 0), PROTO_N - 1);
        const float* r0 = src + iyA * PROTO_N;
        const float* r1 = src + iyB * PROTO_N;
        float v0 = r0[ixA] * (1.0f - fx) + r0[ixB] * fx;
        float v1 = r1[ixA] * (1.0f - fx) + r1[ixB] * fx;
        float mv = v0 * (1.0f - fy) + v1 * fy;
        out[((size_t)bn * OUT_N + oy) * OUT_N + ox] = (val && mv > 0.5f) ? 1.0f : 0.0f;
    }
}

// ---------------------------------------------------------------------------
extern "C" void kernel_launch(void* const* d_in, const int* in_sizes, int n_in,
                              void* d_out, int out_size, void* d_ws, size_t ws_size,
                              hipStream_t stream)
{
    const float* cls   = (const float*)d_in[0];
    const float* boxd  = (const float*)d_in[1];
    const float* coef  = (const float*)d_in[2];
    const float* proto = (const float*)d_in[3];
    const float* anch  = (const float*)d_in[4];
    float* out = (float*)d_out;

    char* ws = (char*)d_ws;
    size_t off = 0;
    auto alloc = [&](size_t bytes) -> void* {
        void* p = ws + off;
        off += (bytes + 255) & ~(size_t)255;
        return p;
    };
    float* S         = (float*)alloc((size_t)B_N * FG * A_N * 4);          // 11.9 MB
    float* boxes     = (float*)alloc((size_t)B_N * A_N * 4 * 4);           // 0.6 MB
    int*   det_idx   = (int*)  alloc((size_t)B_N * FG * TOPN * 4);
    float* det_score = (float*)alloc((size_t)B_N * FG * TOPN * 4);
    float* flat      = (float*)alloc((size_t)B_N * FLATN * 4);
    int*   sel_anchor= (int*)  alloc((size_t)B_N * MAXOBJ * 4);
    int*   sel_valid = (int*)  alloc((size_t)B_N * MAXOBJ * 4);
    float* crop      = (float*)alloc((size_t)B_N * MAXOBJ * 4 * 4);
    float* maskbuf   = (float*)alloc((size_t)B_N * MAXOBJ * PROTO_N * PROTO_N * 4); // 14.8 MB
    (void)ws_size; (void)in_sizes; (void)n_in; (void)out_size;

    float* lab = out + MASK_ELEMS;
    float* sco = lab + B_N * MAXOBJ;
    float* va  = sco + B_N * MAXOBJ;

    k_decode<<<(B_N * A_N + 255) / 256, 256, 0, stream>>>(cls, boxd, anch, S, boxes);
    k_topk<<<B_N * FG, 512, ((A_N * 4 + 127) & ~127), stream>>>(S, det_idx, det_score);
    k_nms<<<B_N * FG, 256, 0, stream>>>(boxes, det_idx, det_score, flat);
    k_top100<<<B_N, 1024, 0, stream>>>(flat, det_idx, boxes, lab, sco, va,
                                       sel_anchor, sel_valid, crop);
    k_mask<<<B_N * PROTO_N, 256, 0, stream>>>(proto, coef, sel_anchor, crop, maskbuf);
    k_resize<<<B_N * MAXOBJ * 8, 256, 0, stream>>>(maskbuf, sel_valid, out);
}

// Round 2
// 292.284 us; speedup vs baseline: 4.5262x; 4.5262x over previous
//
#include <hip/hip_runtime.h>
#include <math.h>

#define A_N     18525
#define B_N     2
#define NCLS    81
#define FG      80
#define TOPN    200
#define MAXOBJ  100
#define PROTO_N 136
#define OUT_N   544
#define COEF_N  32
#define FLATN   (FG*TOPN)      // 16000
#define MIN_SCORE 0.05f
#define NMS_T   0.5f
#define MASK_ELEMS ((size_t)B_N*MAXOBJ*OUT_N*OUT_N)  // 59,187,200

// monotone float<->uint order map (no NaNs in our data)
__device__ __forceinline__ uint32_t ordf(float x) {
    uint32_t u = __float_as_uint(x);
    return (u & 0x80000000u) ? ~u : (u | 0x80000000u);
}
__device__ __forceinline__ float unordf(uint32_t u) {
    return (u & 0x80000000u) ? __uint_as_float(u & 0x7FFFFFFFu)
                             : __uint_as_float(~u);
}

// ---------------------------------------------------------------------------
// One-shot exact top-NSEL select + sort over NELEM elements.
// Composite key (value-desc, index-asc, all distinct):
//   K(i) = (ord(v[i]) << 32) | (0xFFFFFFFF - i)
// vo[NELEM] : ordered value bits (LDS), hist[256] (LDS),
// list[NSORT] u64 (LDS, output: keys sorted descending), ctrl[4] (LDS).
// Per-thread alive/selected bitmasks over its strided elements (NPT <= 64).
// ---------------------------------------------------------------------------
template<int NELEM, int NTH, int NSEL, int NSORT>
__device__ void topk_select_sort(uint32_t* vo, uint32_t* hist,
                                 unsigned long long* list, int* ctrl, int tid)
{
    unsigned long long alive = 0ull, sel = 0ull;
    int nown = (tid < NELEM) ? ((NELEM - 1 - tid) / NTH + 1) : 0;
    alive = (nown >= 64) ? ~0ull : ((1ull << nown) - 1ull);
    if (tid == 0) { ctrl[0] = NSEL; ctrl[2] = 0; ctrl[3] = 0; }
    __syncthreads();

    for (int p = 7; p >= 0; --p) {
        for (int d = tid; d < 256; d += NTH) hist[d] = 0u;
        __syncthreads();
        {
            int j = 0;
            for (int i = tid; i < NELEM; i += NTH, ++j) {
                if ((alive >> j) & 1ull) {
                    unsigned long long K =
                        ((unsigned long long)vo[i] << 32) | (0xFFFFFFFFu - (uint32_t)i);
                    uint32_t d = (uint32_t)(K >> (8 * p)) & 255u;
                    atomicAdd(&hist[d], 1u);
                }
            }
        }
        __syncthreads();
        if (tid == 0) {
            int R = ctrl[0];
            uint32_t cum = 0; int bnd = 0;
            for (int d = 255; d >= 0; --d) {
                uint32_t h = hist[d];
                if (cum + h >= (uint32_t)R) { bnd = d; break; }
                cum += h;
            }
            int Rb = R - (int)cum;               // still needed from boundary bucket
            ctrl[0] = Rb;
            ctrl[1] = bnd;
            ctrl[2] = (hist[bnd] == (uint32_t)Rb) ? 1 : 0;  // whole bucket selected?
        }
        __syncthreads();
        int bnd  = ctrl[1];
        int done = ctrl[2];
        {
            int j = 0;
            for (int i = tid; i < NELEM; i += NTH, ++j) {
                if ((alive >> j) & 1ull) {
                    unsigned long long K =
                        ((unsigned long long)vo[i] << 32) | (0xFFFFFFFFu - (uint32_t)i);
                    uint32_t d = (uint32_t)(K >> (8 * p)) & 255u;
                    if (d > (uint32_t)bnd || (done && d == (uint32_t)bnd)) {
                        sel |= 1ull << j; alive &= ~(1ull << j);
                    } else if (d < (uint32_t)bnd) {
                        alive &= ~(1ull << j);
                    }
                }
            }
        }
        __syncthreads();
        if (done) break;
        // at p==0 keys are fully distinct -> boundary bucket has 1 elem == Rb -> done
    }

    // compact exactly NSEL selected keys (unordered), pad to NSORT with 0
    {
        int j = 0;
        for (int i = tid; i < NELEM; i += NTH, ++j) {
            if ((sel >> j) & 1ull) {
                int pos = atomicAdd(&ctrl[3], 1);
                list[pos] = ((unsigned long long)vo[i] << 32) | (0xFFFFFFFFu - (uint32_t)i);
            }
        }
    }
    for (int i = NSEL + tid; i < NSORT; i += NTH) list[i] = 0ull;
    __syncthreads();

    // bitonic sort descending on NSORT u64 keys
    for (int k = 2; k <= NSORT; k <<= 1) {
        for (int j = k >> 1; j > 0; j >>= 1) {
            for (int t = tid; t < NSORT; t += NTH) {
                int ixj = t ^ j;
                if (ixj > t) {
                    bool up = ((t & k) == 0);
                    unsigned long long a = list[t], b = list[ixj];
                    if ((a < b) == up) { list[t] = b; list[ixj] = a; }
                }
            }
            __syncthreads();
        }
    }
}

// ---------------------------------------------------------------------------
// Kernel 1: softmax + anchor-valid mask + box decode.
// S[b][c][a] = anchor_valid ? softmax_fg_score : -1.0f   (class-major layout)
// ---------------------------------------------------------------------------
__global__ __launch_bounds__(256) void k_decode(
    const float* __restrict__ cls, const float* __restrict__ boxd,
    const float* __restrict__ anchors,
    float* __restrict__ S, float* __restrict__ boxes)
{
    int idx = blockIdx.x * 256 + threadIdx.x;
    if (idx >= B_N * A_N) return;
    int b = idx / A_N, a = idx - b * A_N;
    const float* cl = cls + (size_t)idx * NCLS;

    float mx = cl[0];
    for (int i = 1; i < NCLS; ++i) mx = fmaxf(mx, cl[i]);
    float sum = 0.0f, mfg = -1e30f;
    for (int i = 0; i < NCLS; ++i) {
        float x = cl[i];
        sum += expf(x - mx);
        if (i > 0) mfg = fmaxf(mfg, x);
    }
    float inv = 1.0f / sum;
    int valid = (expf(mfg - mx) * inv) > MIN_SCORE;  // strict >

    for (int c = 0; c < FG; ++c) {
        float s = expf(cl[c + 1] - mx) * inv;
        S[((size_t)b * FG + c) * A_N + a] = valid ? s : -1.0f;
    }

    const float* an = anchors + (size_t)a * 4;
    const float* bd = boxd + (size_t)idx * 4;
    float aw = an[2], ah = an[3];
    float cx = an[0] + bd[0] * 0.1f * aw;
    float cy = an[1] + bd[1] * 0.1f * ah;
    float w  = aw * expf(bd[2] * 0.2f);
    float h  = ah * expf(bd[3] * 0.2f);
    float x1 = cx - w * 0.5f, y1 = cy - h * 0.5f;
    float x2 = x1 + w,        y2 = y1 + h;
    x1 = fminf(fmaxf(x1, 0.0f), 1.0f);
    y1 = fminf(fmaxf(y1, 0.0f), 1.0f);
    x2 = fminf(fmaxf(x2, 0.0f), 1.0f);
    y2 = fminf(fmaxf(y2, 0.0f), 1.0f);
    float* bo = boxes + (size_t)idx * 4;
    bo[0] = x1; bo[1] = y1; bo[2] = x2; bo[3] = y2;
}

// ---------------------------------------------------------------------------
// Kernel 2: per-(b,c) exact top-200 via radix select + bitonic sort.
// ---------------------------------------------------------------------------
#define TOPK_LDS (256*8 + A_N*4 + 256*4 + 16)
__global__ __launch_bounds__(512) void k_topk(
    const float* __restrict__ S, int* __restrict__ det_idx,
    float* __restrict__ det_score)
{
    extern __shared__ unsigned char smem[];
    unsigned long long* list = (unsigned long long*)smem;
    uint32_t* vo   = (uint32_t*)(smem + 256 * 8);
    uint32_t* hist = vo + A_N;
    int*      ctrl = (int*)(hist + 256);

    int bc = blockIdx.x;                  // b*FG + c
    int tid = threadIdx.x;
    const float* row = S + (size_t)bc * A_N;
    for (int i = tid; i < A_N; i += 512) vo[i] = ordf(row[i]);
    __syncthreads();

    topk_select_sort<A_N, 512, TOPN, 256>(vo, hist, list, ctrl, tid);

    for (int t = tid; t < TOPN; t += 512) {
        unsigned long long K = list[t];
        det_idx[bc * TOPN + t]   = (int)(0xFFFFFFFFu - (uint32_t)K);
        det_score[bc * TOPN + t] = unordf((uint32_t)(K >> 32));
    }
}

// ---------------------------------------------------------------------------
// Kernel 3: fast NMS per (b,c). flat[b][c*200+j] = keep ? score : -inf
// ---------------------------------------------------------------------------
__global__ __launch_bounds__(256) void k_nms(
    const float* __restrict__ boxes, const int* __restrict__ det_idx,
    const float* __restrict__ det_score, float* __restrict__ flat)
{
    __shared__ float bx1[TOPN], by1[TOPN], bx2[TOPN], by2[TOPN], ar[TOPN], sc[TOPN];
    __shared__ int dv[TOPN];
    int bc = blockIdx.x;
    int b = bc / FG, c = bc - b * FG;
    int tid = threadIdx.x;
    if (tid < TOPN) {
        int a = det_idx[bc * TOPN + tid];
        const float* bo = boxes + ((size_t)b * A_N + a) * 4;
        float x1 = bo[0], y1 = bo[1], x2 = bo[2], y2 = bo[3];
        bx1[tid] = x1; by1[tid] = y1; bx2[tid] = x2; by2[tid] = y2;
        ar[tid] = (x2 - x1) * (y2 - y1);
        float s = det_score[bc * TOPN + tid];
        sc[tid] = s;
        dv[tid] = (s > -0.5f) ? 1 : 0;   // invalid anchors stored as exactly -1.0
    }
    __syncthreads();
    if (tid < TOPN) {
        float x1 = bx1[tid], y1 = by1[tid], x2 = bx2[tid], y2 = by2[tid];
        float aj = ar[tid];
        bool sup = false;
        for (int i = 0; i < tid; ++i) {
            float iw = fmaxf(fminf(bx2[i], x2) - fmaxf(bx1[i], x1), 0.0f);
            float ih = fmaxf(fminf(by2[i], y2) - fmaxf(by1[i], y1), 0.0f);
            float inter = iw * ih;
            float iou = inter / (ar[i] + aj - inter);   // may be NaN (0/0)
            // reference: iou * det_valid[i] (NaN survives *0), keep = max <= T
            bool bad = dv[i] ? !(iou <= NMS_T) : isnan(iou);
            if (bad) sup = true;
        }
        bool keep = dv[tid] && !sup;
        flat[(size_t)b * FLATN + c * TOPN + tid] = keep ? sc[tid] : -INFINITY;
    }
}

// ---------------------------------------------------------------------------
// Kernel 4: global top-100 per batch via radix select + sort; parallel epilogue.
// ---------------------------------------------------------------------------
#define TOP100_LDS (128*8 + FLATN*4 + 256*4 + 16)
__global__ __launch_bounds__(1024) void k_top100(
    const float* __restrict__ flat, const int* __restrict__ det_idx,
    const float* __restrict__ boxes,
    float* __restrict__ lab, float* __restrict__ sco, float* __restrict__ va,
    int* __restrict__ sel_anchor, int* __restrict__ sel_valid,
    float* __restrict__ crop)
{
    extern __shared__ unsigned char smem[];
    unsigned long long* list = (unsigned long long*)smem;
    uint32_t* vo   = (uint32_t*)(smem + 128 * 8);
    uint32_t* hist = vo + FLATN;
    int*      ctrl = (int*)(hist + 256);

    int b = blockIdx.x;
    int tid = threadIdx.x;
    for (int i = tid; i < FLATN; i += 1024) vo[i] = ordf(flat[(size_t)b * FLATN + i]);
    __syncthreads();

    topk_select_sort<FLATN, 1024, MAXOBJ, 128>(vo, hist, list, ctrl, tid);

    if (tid < MAXOBJ) {
        unsigned long long K = list[tid];
        int fi = (int)(0xFFFFFFFFu - (uint32_t)K);
        float fv = unordf((uint32_t)(K >> 32));
        int valid = (fv > -1e37f) ? 1 : 0;          // isfinite (scores in (0,1])
        int c = fi / TOPN, t = fi - c * TOPN;
        int anchor = det_idx[((size_t)b * FG + c) * TOPN + t];
        lab[b * MAXOBJ + tid] = valid ? (float)c : -1.0f;
        sco[b * MAXOBJ + tid] = valid ? fv : 0.0f;
        va [b * MAXOBJ + tid] = valid ? 1.0f : 0.0f;
        sel_anchor[b * MAXOBJ + tid] = anchor;
        sel_valid [b * MAXOBJ + tid] = valid;
        const float* bo = boxes + ((size_t)b * A_N + anchor) * 4;
        float xlo = fminf(bo[0], bo[2]), xhi = fmaxf(bo[0], bo[2]);
        float ylo = fminf(bo[1], bo[3]), yhi = fmaxf(bo[1], bo[3]);
        float* cr = crop + ((size_t)b * MAXOBJ + tid) * 4;
        cr[0] = fmaxf(xlo * (float)PROTO_N - 1.0f, 0.0f);
        cr[1] = fminf(xhi * (float)PROTO_N + 1.0f, (float)PROTO_N);
        cr[2] = fmaxf(ylo * (float)PROTO_N - 1.0f, 0.0f);
        cr[3] = fminf(yhi * (float)PROTO_N + 1.0f, (float)PROTO_N);
    }
}

// ---------------------------------------------------------------------------
// Kernel 5: proto @ coef^T -> sigmoid -> crop, at proto resolution.
// ---------------------------------------------------------------------------
__global__ __launch_bounds__(256) void k_mask(
    const float* __restrict__ proto, const float* __restrict__ coefs,
    const int* __restrict__ sel_anchor, const float* __restrict__ crop,
    float* __restrict__ maskbuf)
{
    __shared__ float prow[PROTO_N * 33];     // bank-conflict-free stride
    __shared__ float cf[MAXOBJ * COEF_N];
    __shared__ float cb[MAXOBJ][4];
    int blk = blockIdx.x;
    int b = blk / PROTO_N, y = blk - b * PROTO_N;
    int tid = threadIdx.x;

    const float* pr = proto + ((size_t)(b * PROTO_N + y) * PROTO_N) * COEF_N;
    for (int i = tid; i < PROTO_N * COEF_N; i += 256) {
        int x = i >> 5, c = i & 31;
        prow[x * 33 + c] = pr[i];
    }
    for (int i = tid; i < MAXOBJ * COEF_N; i += 256) {
        int n = i >> 5, c = i & 31;
        cf[i] = coefs[((size_t)b * A_N + sel_anchor[b * MAXOBJ + n]) * COEF_N + c];
    }
    if (tid < MAXOBJ) {
        const float* cr = crop + ((size_t)b * MAXOBJ + tid) * 4;
        cb[tid][0] = cr[0]; cb[tid][1] = cr[1]; cb[tid][2] = cr[2]; cb[tid][3] = cr[3];
    }
    __syncthreads();

    float yf = (float)y;
    for (int idx = tid; idx < MAXOBJ * PROTO_N; idx += 256) {
        int n = idx / PROTO_N, x = idx - n * PROTO_N;
        const float* pp = prow + x * 33;
        const float* cp = cf + n * COEF_N;
        float d = 0.0f;
        #pragma unroll
        for (int c = 0; c < COEF_N; ++c) d = fmaf(pp[c], cp[c], d);
        float m = 1.0f / (1.0f + expf(-d));
        float xf = (float)x;
        bool keep = (xf >= cb[n][0]) && (xf < cb[n][1]) &&
                    (yf >= cb[n][2]) && (yf < cb[n][3]);
        maskbuf[(((size_t)b * MAXOBJ + n) * PROTO_N + y) * PROTO_N + x] = keep ? m : 0.0f;
    }
}

// ---------------------------------------------------------------------------
// Kernel 6: bilinear x4 upsample + valid gate + >0.5 threshold.
// ---------------------------------------------------------------------------
__global__ __launch_bounds__(256) void k_resize(
    const float* __restrict__ maskbuf, const int* __restrict__ sel_valid,
    float* __restrict__ out)
{
    __shared__ float src[19 * PROTO_N];
    int blk = blockIdx.x;            // B*100*8
    int tile = blk & 7;
    int bn = blk >> 3;               // b*100+n
    int tid = threadIdx.x;

    int oy0 = tile * 68;
    float sy0 = (oy0 + 0.5f) * 0.25f - 0.5f;
    float sy1 = (oy0 + 67 + 0.5f) * 0.25f - 0.5f;
    int iy_lo = max((int)floorf(sy0), 0);
    int iy_hi = min((int)floorf(sy1) + 1, PROTO_N - 1);
    int nrows = iy_hi - iy_lo + 1;

    const float* mb = maskbuf + ((size_t)bn * PROTO_N + iy_lo) * PROTO_N;
    for (int i = tid; i < nrows * PROTO_N; i += 256) src[i] = mb[i];
    int val = sel_valid[bn];
    __syncthreads();

    for (int p = tid; p < 68 * OUT_N; p += 256) {
        int oy = oy0 + p / OUT_N;
        int ox = p - (p / OUT_N) * OUT_N;
        float sy = (oy + 0.5f) * 0.25f - 0.5f;
        int iy0 = (int)floorf(sy);
        float fy = sy - (float)iy0;
        int iyA = min(max(iy0, 0), PROTO_N - 1) - iy_lo;
        int iyB = min(max(iy0 + 1, 0), PROTO_N - 1) - iy_lo;
        float sx = (ox + 0.5f) * 0.25f - 0.5f;
        int ix0 = (int)floorf(sx);
        float fx = sx - (float)ix0;
        int ixA = min(max(ix0, 0), PROTO_N - 1);
        int ixB = min(max(ix0 + 1, 0), PROTO_N - 1);
        const float* r0 = src + iyA * PROTO_N;
        const float* r1 = src + iyB * PROTO_N;
        float v0 = r0[ixA] * (1.0f - fx) + r0[ixB] * fx;
        float v1 = r1[ixA] * (1.0f - fx) + r1[ixB] * fx;
        float mv = v0 * (1.0f - fy) + v1 * fy;
        out[((size_t)bn * OUT_N + oy) * OUT_N + ox] = (val && mv > 0.5f) ? 1.0f : 0.0f;
    }
}

// ---------------------------------------------------------------------------
extern "C" void kernel_launch(void* const* d_in, const int* in_sizes, int n_in,
                              void* d_out, int out_size, void* d_ws, size_t ws_size,
                              hipStream_t stream)
{
    const float* cls   = (const float*)d_in[0];
    const float* boxd  = (const float*)d_in[1];
    const float* coef  = (const float*)d_in[2];
    const float* proto = (const float*)d_in[3];
    const float* anch  = (const float*)d_in[4];
    float* out = (float*)d_out;

    char* ws = (char*)d_ws;
    size_t off = 0;
    auto alloc = [&](size_t bytes) -> void* {
        void* p = ws + off;
        off += (bytes + 255) & ~(size_t)255;
        return p;
    };
    float* S         = (float*)alloc((size_t)B_N * FG * A_N * 4);
    float* boxes     = (float*)alloc((size_t)B_N * A_N * 4 * 4);
    int*   det_idx   = (int*)  alloc((size_t)B_N * FG * TOPN * 4);
    float* det_score = (float*)alloc((size_t)B_N * FG * TOPN * 4);
    float* flat      = (float*)alloc((size_t)B_N * FLATN * 4);
    int*   sel_anchor= (int*)  alloc((size_t)B_N * MAXOBJ * 4);
    int*   sel_valid = (int*)  alloc((size_t)B_N * MAXOBJ * 4);
    float* crop      = (float*)alloc((size_t)B_N * MAXOBJ * 4 * 4);
    float* maskbuf   = (float*)alloc((size_t)B_N * MAXOBJ * PROTO_N * PROTO_N * 4);
    (void)ws_size; (void)in_sizes; (void)n_in; (void)out_size;

    float* lab = out + MASK_ELEMS;
    float* sco = lab + B_N * MAXOBJ;
    float* va  = sco + B_N * MAXOBJ;

    k_decode<<<(B_N * A_N + 255) / 256, 256, 0, stream>>>(cls, boxd, anch, S, boxes);
    k_topk<<<B_N * FG, 512, TOPK_LDS, stream>>>(S, det_idx, det_score);
    k_nms<<<B_N * FG, 256, 0, stream>>>(boxes, det_idx, det_score, flat);
    k_top100<<<B_N, 1024, TOP100_LDS, stream>>>(flat, det_idx, boxes, lab, sco, va,
                                                sel_anchor, sel_valid, crop);
    k_mask<<<B_N * PROTO_N, 256, 0, stream>>>(proto, coef, sel_anchor, crop, maskbuf);
    k_resize<<<B_N * MAXOBJ * 8, 256, 0, stream>>>(maskbuf, sel_valid, out);
}

// Round 3
// 212.192 us; speedup vs baseline: 6.2346x; 1.3775x over previous
//
#include <hip/hip_runtime.h>
#include <math.h>

#define A_N     18525
#define A_PAD   18528          // padded row stride (uint4-aligned)
#define B_N     2
#define NCLS    81
#define FG      80
#define TOPN    200
#define MAXOBJ  100
#define PROTO_N 136
#define OUT_N   544
#define COEF_N  32
#define FLATN   (FG*TOPN)      // 16000
#define MIN_SCORE 0.05f
#define NMS_T   0.5f
#define MASK_ELEMS ((size_t)B_N*MAXOBJ*OUT_N*OUT_N)  // 59,187,200

#define ORD_NEG1 0x407FFFFFu   // ordf(-1.0f)
#define ORD_NINF 0x007FFFFFu   // ordf(-inf)

// monotone float<->uint order map (no NaNs in our data)
__device__ __forceinline__ uint32_t ordf(float x) {
    uint32_t u = __float_as_uint(x);
    return (u & 0x80000000u) ? ~u : (u | 0x80000000u);
}
__device__ __forceinline__ float unordf(uint32_t u) {
    return (u & 0x80000000u) ? __uint_as_float(u & 0x7FFFFFFFu)
                             : __uint_as_float(~u);
}

// ---------------------------------------------------------------------------
// Exact top-NSEL select + descending sort over NELEM ordered-uint values.
// Composite key (value-desc, index-asc, all distinct):
//   K(i) = (vo[i] << 32) | (0xFFFFFFFF - i)
// Per-wave histograms + parallel suffix-scan boundary detection.
// ---------------------------------------------------------------------------
template<int NELEM, int NTH, int NW, int NSEL, int NSORT>
__device__ void topk_select_sort(const uint32_t* vo, uint32_t* whist,
                                 uint32_t* tot, uint32_t* suf,
                                 unsigned long long* list, int* ctrl, int tid)
{
    unsigned long long alive = 0ull, sel = 0ull;
    int nown = (tid < NELEM) ? ((NELEM - 1 - tid) / NTH + 1) : 0;
    alive = (nown >= 64) ? ~0ull : ((1ull << nown) - 1ull);
    if (tid == 0) { ctrl[0] = NSEL; ctrl[3] = 0; }
    int wid = tid >> 6;
    __syncthreads();

    for (int p = 7; p >= 0; --p) {
        for (int i = tid; i < NW * 256; i += NTH) whist[i] = 0u;
        __syncthreads();
        {
            int j = 0;
            for (int i = tid; i < NELEM; i += NTH, ++j) {
                if ((alive >> j) & 1ull) {
                    unsigned long long K =
                        ((unsigned long long)vo[i] << 32) | (0xFFFFFFFFu - (uint32_t)i);
                    uint32_t d = (uint32_t)(K >> (8 * p)) & 255u;
                    atomicAdd(&whist[wid * 256 + d], 1u);
                }
            }
        }
        __syncthreads();
        if (tid < 256) {
            uint32_t s = 0;
            #pragma unroll
            for (int w = 0; w < NW; ++w) s += whist[w * 256 + tid];
            tot[tid] = s; suf[tid] = s;
        }
        __syncthreads();
        // inclusive suffix sum over 256 buckets (high->low)
        for (int off = 1; off < 256; off <<= 1) {
            uint32_t v_ = 0;
            if (tid < 256) v_ = suf[tid] + ((tid + off < 256) ? suf[tid + off] : 0u);
            __syncthreads();
            if (tid < 256) suf[tid] = v_;
            __syncthreads();
        }
        int R = ctrl[0];
        __syncthreads();
        if (tid < 256) {
            uint32_t sInc = suf[tid];
            uint32_t sAb  = (tid < 255) ? suf[tid + 1] : 0u;
            if (sInc >= (uint32_t)R && sAb < (uint32_t)R) {
                int Rb = R - (int)sAb;
                ctrl[0] = Rb; ctrl[1] = tid;
                ctrl[2] = (tot[tid] == (uint32_t)Rb) ? 1 : 0;
            }
        }
        __syncthreads();
        int bnd  = ctrl[1];
        int done = ctrl[2];
        {
            int j = 0;
            for (int i = tid; i < NELEM; i += NTH, ++j) {
                if ((alive >> j) & 1ull) {
                    unsigned long long K =
                        ((unsigned long long)vo[i] << 32) | (0xFFFFFFFFu - (uint32_t)i);
                    uint32_t d = (uint32_t)(K >> (8 * p)) & 255u;
                    if (d > (uint32_t)bnd || (done && d == (uint32_t)bnd)) {
                        sel |= 1ull << j; alive &= ~(1ull << j);
                    } else if (d < (uint32_t)bnd) {
                        alive &= ~(1ull << j);
                    }
                }
            }
        }
        __syncthreads();
        if (done) break;   // at p==0 keys are distinct -> always done
    }

    // compact exactly NSEL selected keys (unordered), pad to NSORT with 0
    {
        int j = 0;
        for (int i = tid; i < NELEM; i += NTH, ++j) {
            if ((sel >> j) & 1ull) {
                int pos = atomicAdd(&ctrl[3], 1);
                list[pos] = ((unsigned long long)vo[i] << 32) | (0xFFFFFFFFu - (uint32_t)i);
            }
        }
    }
    for (int i = NSEL + tid; i < NSORT; i += NTH) list[i] = 0ull;
    __syncthreads();

    // bitonic sort descending on NSORT u64 keys
    for (int k = 2; k <= NSORT; k <<= 1) {
        for (int j = k >> 1; j > 0; j >>= 1) {
            for (int t = tid; t < NSORT; t += NTH) {
                int ixj = t ^ j;
                if (ixj > t) {
                    bool up = ((t & k) == 0);
                    unsigned long long a = list[t], b = list[ixj];
                    if ((a < b) == up) { list[t] = b; list[ixj] = a; }
                }
            }
            __syncthreads();
        }
    }
}

// ---------------------------------------------------------------------------
// Kernel 1: softmax + anchor-valid mask + box decode. Row cached in registers.
// S[b][c][a] (stride A_PAD) = ordered uint of (valid ? score : -1.0f)
// ---------------------------------------------------------------------------
__global__ __launch_bounds__(256) void k_decode(
    const float* __restrict__ cls, const float* __restrict__ boxd,
    const float* __restrict__ anchors,
    uint32_t* __restrict__ S, float* __restrict__ boxes)
{
    int idx = blockIdx.x * 256 + threadIdx.x;
    // pad writers (rows have 3 pad entries each; value 0 ranks below everything)
    if (idx < B_N * FG * 3) {
        int row = idx / 3, j = idx - row * 3;
        S[(size_t)row * A_PAD + A_N + j] = 0u;
    }
    if (idx >= B_N * A_N) return;
    int b = idx / A_N, a = idx - b * A_N;
    const float* cl = cls + (size_t)idx * NCLS;

    float r[NCLS];
    #pragma unroll
    for (int i = 0; i < NCLS; ++i) r[i] = cl[i];
    float mx = r[0];
    #pragma unroll
    for (int i = 1; i < NCLS; ++i) mx = fmaxf(mx, r[i]);
    float sum = 0.0f, mfg = 0.0f;
    #pragma unroll
    for (int i = 0; i < NCLS; ++i) {
        float e = __expf(r[i] - mx) ;
        e = expf(r[i] - mx);           // keep libm expf for bit-match with r1
        sum += e;
        r[i] = e;
        if (i > 0) mfg = fmaxf(mfg, e);
    }
    float inv = 1.0f / sum;
    int valid = (mfg * inv) > MIN_SCORE;  // strict >

    #pragma unroll
    for (int c = 0; c < FG; ++c) {
        float s = r[c + 1] * inv;
        S[((size_t)b * FG + c) * A_PAD + a] = valid ? ordf(s) : ORD_NEG1;
    }

    const float* an = anchors + (size_t)a * 4;
    const float* bd = boxd + (size_t)idx * 4;
    float aw = an[2], ah = an[3];
    float cx = an[0] + bd[0] * 0.1f * aw;
    float cy = an[1] + bd[1] * 0.1f * ah;
    float w  = aw * expf(bd[2] * 0.2f);
    float h  = ah * expf(bd[3] * 0.2f);
    float x1 = cx - w * 0.5f, y1 = cy - h * 0.5f;
    float x2 = x1 + w,        y2 = y1 + h;
    x1 = fminf(fmaxf(x1, 0.0f), 1.0f);
    y1 = fminf(fmaxf(y1, 0.0f), 1.0f);
    x2 = fminf(fmaxf(x2, 0.0f), 1.0f);
    y2 = fminf(fmaxf(y2, 0.0f), 1.0f);
    float* bo = boxes + (size_t)idx * 4;
    bo[0] = x1; bo[1] = y1; bo[2] = x2; bo[3] = y2;
}

// ---------------------------------------------------------------------------
// Kernel 2: per-(b,c) exact top-200 via radix select + bitonic sort.
// ---------------------------------------------------------------------------
#define TOPK_NTH 1024
#define TOPK_NW  (TOPK_NTH/64)
#define TOPK_LDS (A_PAD*4 + 256*8 + TOPK_NW*256*4 + 256*4 + 256*4 + 32)
__global__ __launch_bounds__(TOPK_NTH) void k_topk(
    const uint32_t* __restrict__ S, int* __restrict__ det_idx,
    float* __restrict__ det_score)
{
    extern __shared__ unsigned char smem[];
    uint32_t* vo = (uint32_t*)smem;                                // A_PAD
    unsigned long long* list = (unsigned long long*)(smem + A_PAD*4);   // 256
    uint32_t* whist = (uint32_t*)(smem + A_PAD*4 + 256*8);
    uint32_t* tot   = whist + TOPK_NW*256;
    uint32_t* suf   = tot + 256;
    int*      ctrl  = (int*)(suf + 256);

    int bc = blockIdx.x;                  // b*FG + c
    int tid = threadIdx.x;
    const uint4* row4 = (const uint4*)(S + (size_t)bc * A_PAD);
    for (int i = tid; i < A_PAD/4; i += TOPK_NTH) ((uint4*)vo)[i] = row4[i];
    __syncthreads();

    topk_select_sort<A_PAD, TOPK_NTH, TOPK_NW, TOPN, 256>(vo, whist, tot, suf, list, ctrl, tid);

    if (tid < TOPN) {
        unsigned long long K = list[tid];
        det_idx[bc * TOPN + tid]   = (int)(0xFFFFFFFFu - (uint32_t)K);
        det_score[bc * TOPN + tid] = unordf((uint32_t)(K >> 32));
    }
}

// ---------------------------------------------------------------------------
// Kernel 3: fast NMS per (b,c). flat_ord = keep ? ordf(score) : ordf(-inf)
// ---------------------------------------------------------------------------
__global__ __launch_bounds__(256) void k_nms(
    const float* __restrict__ boxes, const int* __restrict__ det_idx,
    const float* __restrict__ det_score, uint32_t* __restrict__ flat)
{
    __shared__ float bx1[TOPN], by1[TOPN], bx2[TOPN], by2[TOPN], ar[TOPN], sc[TOPN];
    __shared__ int dv[TOPN];
    int bc = blockIdx.x;
    int b = bc / FG, c = bc - b * FG;
    int tid = threadIdx.x;
    if (tid < TOPN) {
        int a = det_idx[bc * TOPN + tid];
        const float* bo = boxes + ((size_t)b * A_N + a) * 4;
        float x1 = bo[0], y1 = bo[1], x2 = bo[2], y2 = bo[3];
        bx1[tid] = x1; by1[tid] = y1; bx2[tid] = x2; by2[tid] = y2;
        ar[tid] = (x2 - x1) * (y2 - y1);
        float s = det_score[bc * TOPN + tid];
        sc[tid] = s;
        dv[tid] = (s > -0.5f) ? 1 : 0;   // invalid anchors stored as exactly -1.0
    }
    __syncthreads();
    if (tid < TOPN) {
        float x1 = bx1[tid], y1 = by1[tid], x2 = bx2[tid], y2 = by2[tid];
        float aj = ar[tid];
        bool sup = false;
        for (int i = 0; i < tid; ++i) {
            float iw = fmaxf(fminf(bx2[i], x2) - fmaxf(bx1[i], x1), 0.0f);
            float ih = fmaxf(fminf(by2[i], y2) - fmaxf(by1[i], y1), 0.0f);
            float inter = iw * ih;
            float iou = inter / (ar[i] + aj - inter);   // may be NaN (0/0)
            // reference: iou * det_valid[i] (NaN survives *0), keep = max <= T
            bool bad = dv[i] ? !(iou <= NMS_T) : isnan(iou);
            if (bad) sup = true;
        }
        bool keep = dv[tid] && !sup;
        flat[(size_t)b * FLATN + c * TOPN + tid] = keep ? ordf(sc[tid]) : ORD_NINF;
    }
}

// ---------------------------------------------------------------------------
// Kernel 4: global top-100 per batch via radix select + sort; parallel epilogue.
// ---------------------------------------------------------------------------
#define T100_NTH 1024
#define T100_NW  (T100_NTH/64)
#define TOP100_LDS (FLATN*4 + 128*8 + T100_NW*256*4 + 256*4 + 256*4 + 32)
__global__ __launch_bounds__(T100_NTH) void k_top100(
    const uint32_t* __restrict__ flat, const int* __restrict__ det_idx,
    const float* __restrict__ boxes,
    float* __restrict__ lab, float* __restrict__ sco, float* __restrict__ va,
    int* __restrict__ sel_anchor, int* __restrict__ sel_valid,
    float* __restrict__ crop)
{
    extern __shared__ unsigned char smem[];
    uint32_t* vo = (uint32_t*)smem;                               // FLATN
    unsigned long long* list = (unsigned long long*)(smem + FLATN*4);  // 128
    uint32_t* whist = (uint32_t*)(smem + FLATN*4 + 128*8);
    uint32_t* tot   = whist + T100_NW*256;
    uint32_t* suf   = tot + 256;
    int*      ctrl  = (int*)(suf + 256);

    int b = blockIdx.x;
    int tid = threadIdx.x;
    const uint4* f4 = (const uint4*)(flat + (size_t)b * FLATN);
    for (int i = tid; i < FLATN/4; i += T100_NTH) ((uint4*)vo)[i] = f4[i];
    __syncthreads();

    topk_select_sort<FLATN, T100_NTH, T100_NW, MAXOBJ, 128>(vo, whist, tot, suf, list, ctrl, tid);

    if (tid < MAXOBJ) {
        unsigned long long K = list[tid];
        int fi = (int)(0xFFFFFFFFu - (uint32_t)K);
        float fv = unordf((uint32_t)(K >> 32));
        int valid = (fv > -1e37f) ? 1 : 0;          // isfinite (scores in (0,1])
        int c = fi / TOPN, t = fi - c * TOPN;
        int anchor = det_idx[((size_t)b * FG + c) * TOPN + t];
        lab[b * MAXOBJ + tid] = valid ? (float)c : -1.0f;
        sco[b * MAXOBJ + tid] = valid ? fv : 0.0f;
        va [b * MAXOBJ + tid] = valid ? 1.0f : 0.0f;
        sel_anchor[b * MAXOBJ + tid] = anchor;
        sel_valid [b * MAXOBJ + tid] = valid;
        const float* bo = boxes + ((size_t)b * A_N + anchor) * 4;
        float xlo = fminf(bo[0], bo[2]), xhi = fmaxf(bo[0], bo[2]);
        float ylo = fminf(bo[1], bo[3]), yhi = fmaxf(bo[1], bo[3]);
        float* cr = crop + ((size_t)b * MAXOBJ + tid) * 4;
        cr[0] = fmaxf(xlo * (float)PROTO_N - 1.0f, 0.0f);
        cr[1] = fminf(xhi * (float)PROTO_N + 1.0f, (float)PROTO_N);
        cr[2] = fmaxf(ylo * (float)PROTO_N - 1.0f, 0.0f);
        cr[3] = fminf(yhi * (float)PROTO_N + 1.0f, (float)PROTO_N);
    }
}

// ---------------------------------------------------------------------------
// Kernel 5: proto @ coef^T -> sigmoid -> crop, at proto resolution.
// Chunked (n, x-quad) units; coefficient vector cached in registers.
// ---------------------------------------------------------------------------
__global__ __launch_bounds__(256) void k_mask(
    const float* __restrict__ proto, const float* __restrict__ coefs,
    const int* __restrict__ sel_anchor, const float* __restrict__ crop,
    float* __restrict__ maskbuf)
{
    __shared__ float prow[PROTO_N * 33];
    __shared__ float cf[MAXOBJ * COEF_N];
    __shared__ float cb[MAXOBJ][4];
    int blk = blockIdx.x;
    int b = blk / PROTO_N, y = blk - b * PROTO_N;
    int tid = threadIdx.x;

    const float* pr = proto + ((size_t)(b * PROTO_N + y) * PROTO_N) * COEF_N;
    for (int i = tid; i < PROTO_N * COEF_N; i += 256) {
        int x = i >> 5, c = i & 31;
        prow[x * 33 + c] = pr[i];
    }
    for (int i = tid; i < MAXOBJ * COEF_N; i += 256) {
        int n = i >> 5;
        cf[i] = coefs[((size_t)b * A_N + sel_anchor[b * MAXOBJ + n]) * COEF_N + (i & 31)];
    }
    if (tid < MAXOBJ) {
        const float* cr = crop + ((size_t)b * MAXOBJ + tid) * 4;
        cb[tid][0] = cr[0]; cb[tid][1] = cr[1]; cb[tid][2] = cr[2]; cb[tid][3] = cr[3];
    }
    __syncthreads();

    const int QPR = PROTO_N / 4;         // 34 x-quads per row
    const int UNITS = MAXOBJ * QPR;      // 3400
    float yf = (float)y;
    float cp[COEF_N];
    int curn = -1;
    bool rowOK = false;
    float c0 = 0, c1 = 0;
    int u0 = tid * 14;                   // contiguous chunk: cp reuse across units
    for (int s = 0; s < 14; ++s) {
        int u = u0 + s;
        if (u >= UNITS) break;
        int n = u / QPR, xq = u - n * QPR;
        if (n != curn) {
            curn = n;
            #pragma unroll
            for (int c = 0; c < COEF_N; ++c) cp[c] = cf[n * COEF_N + c];
            rowOK = (yf >= cb[n][2]) && (yf < cb[n][3]);
            c0 = cb[n][0]; c1 = cb[n][1];
        }
        int x0 = xq * 4;
        float4 o;
        #pragma unroll
        for (int j = 0; j < 4; ++j) {
            int x = x0 + j;
            const float* pp = prow + x * 33;
            float d = 0.0f;
            #pragma unroll
            for (int c = 0; c < COEF_N; ++c) d = fmaf(pp[c], cp[c], d);
            float m = 1.0f / (1.0f + expf(-d));
            float xf = (float)x;
            bool keep = rowOK && (xf >= c0) && (xf < c1);
            ((float*)&o)[j] = keep ? m : 0.0f;
        }
        *(float4*)&maskbuf[(((size_t)b * MAXOBJ + n) * PROTO_N + y) * PROTO_N + x0] = o;
    }
}

// ---------------------------------------------------------------------------
// Kernel 6: bilinear x4 upsample + valid gate + >0.5, phase-decomposed,
// float4 loads/stores.
// ---------------------------------------------------------------------------
__global__ __launch_bounds__(256) void k_resize(
    const float* __restrict__ maskbuf, const int* __restrict__ sel_valid,
    float* __restrict__ out)
{
    __shared__ float src[19 * PROTO_N];
    int blk = blockIdx.x;            // B*100*8
    int tile = blk & 7;
    int bn = blk >> 3;               // b*100+n
    int tid = threadIdx.x;

    int oy0 = tile * 68;
    float sy0 = (oy0 + 0.5f) * 0.25f - 0.5f;
    float sy1 = (oy0 + 67 + 0.5f) * 0.25f - 0.5f;
    int iy_lo = max((int)floorf(sy0), 0);
    int iy_hi = min((int)floorf(sy1) + 1, PROTO_N - 1);
    int nrows = iy_hi - iy_lo + 1;

    const float4* mb4 = (const float4*)(maskbuf + ((size_t)bn * PROTO_N + iy_lo) * PROTO_N);
    for (int i = tid; i < nrows * (PROTO_N/4); i += 256) ((float4*)src)[i] = mb4[i];
    int val = sel_valid[bn];
    __syncthreads();

    const int QPR = PROTO_N;             // 136 x-quads per output row (544/4)
    const int UNITS = 68 * QPR;          // 9248
    for (int u = tid; u < UNITS; u += 256) {
        int oyl = u / QPR, xq = u - oyl * QPR;
        int oy = oy0 + oyl;
        float sy = (oy + 0.5f) * 0.25f - 0.5f;
        int iy0 = (int)floorf(sy);
        float fy = sy - (float)iy0;
        const float* r0 = src + (min(max(iy0,     0), PROTO_N - 1) - iy_lo) * PROTO_N;
        const float* r1 = src + (min(max(iy0 + 1, 0), PROTO_N - 1) - iy_lo) * PROTO_N;
        // ox = 4*xq + {0,1,2,3}: taps (k-1,k) fx={0.625,0.875}; (k,k+1) fx={0.125,0.375}
        int km = (xq == 0) ? 0 : xq - 1;
        int kp = (xq == PROTO_N - 1) ? PROTO_N - 1 : xq + 1;
        float a0 = r0[km], b0 = r0[xq], cc0 = r0[kp];
        float a1 = r1[km], b1 = r1[xq], cc1 = r1[kp];
        float h00 = a0 * 0.375f + b0 * 0.625f;
        float h01 = a0 * 0.125f + b0 * 0.875f;
        float h02 = b0 * 0.875f + cc0 * 0.125f;
        float h03 = b0 * 0.625f + cc0 * 0.375f;
        float h10 = a1 * 0.375f + b1 * 0.625f;
        float h11 = a1 * 0.125f + b1 * 0.875f;
        float h12 = b1 * 0.875f + cc1 * 0.125f;
        float h13 = b1 * 0.625f + cc1 * 0.375f;
        float g = 1.0f - fy;
        float m0 = h00 * g + h10 * fy;
        float m1 = h01 * g + h11 * fy;
        float m2 = h02 * g + h12 * fy;
        float m3 = h03 * g + h13 * fy;
        float4 o;
        o.x = (val && m0 > 0.5f) ? 1.0f : 0.0f;
        o.y = (val && m1 > 0.5f) ? 1.0f : 0.0f;
        o.z = (val && m2 > 0.5f) ? 1.0f : 0.0f;
        o.w = (val && m3 > 0.5f) ? 1.0f : 0.0f;
        *(float4*)&out[((size_t)bn * OUT_N + oy) * OUT_N + 4 * xq] = o;
    }
}

// ---------------------------------------------------------------------------
extern "C" void kernel_launch(void* const* d_in, const int* in_sizes, int n_in,
                              void* d_out, int out_size, void* d_ws, size_t ws_size,
                              hipStream_t stream)
{
    const float* cls   = (const float*)d_in[0];
    const float* boxd  = (const float*)d_in[1];
    const float* coef  = (const float*)d_in[2];
    const float* proto = (const float*)d_in[3];
    const float* anch  = (const float*)d_in[4];
    float* out = (float*)d_out;

    char* ws = (char*)d_ws;
    size_t off = 0;
    auto alloc = [&](size_t bytes) -> void* {
        void* p = ws + off;
        off += (bytes + 255) & ~(size_t)255;
        return p;
    };
    uint32_t* S      = (uint32_t*)alloc((size_t)B_N * FG * A_PAD * 4);
    float* boxes     = (float*)alloc((size_t)B_N * A_N * 4 * 4);
    int*   det_idx   = (int*)  alloc((size_t)B_N * FG * TOPN * 4);
    float* det_score = (float*)alloc((size_t)B_N * FG * TOPN * 4);
    uint32_t* flat   = (uint32_t*)alloc((size_t)B_N * FLATN * 4);
    int*   sel_anchor= (int*)  alloc((size_t)B_N * MAXOBJ * 4);
    int*   sel_valid = (int*)  alloc((size_t)B_N * MAXOBJ * 4);
    float* crop      = (float*)alloc((size_t)B_N * MAXOBJ * 4 * 4);
    float* maskbuf   = (float*)alloc((size_t)B_N * MAXOBJ * PROTO_N * PROTO_N * 4);
    (void)ws_size; (void)in_sizes; (void)n_in; (void)out_size;

    float* lab = out + MASK_ELEMS;
    float* sco = lab + B_N * MAXOBJ;
    float* va  = sco + B_N * MAXOBJ;

    k_decode<<<(B_N * A_N + 255) / 256, 256, 0, stream>>>(cls, boxd, anch, S, boxes);
    k_topk<<<B_N * FG, TOPK_NTH, TOPK_LDS, stream>>>(S, det_idx, det_score);
    k_nms<<<B_N * FG, 256, 0, stream>>>(boxes, det_idx, det_score, flat);
    k_top100<<<B_N, T100_NTH, TOP100_LDS, stream>>>(flat, det_idx, boxes, lab, sco, va,
                                                    sel_anchor, sel_valid, crop);
    k_mask<<<B_N * PROTO_N, 256, 0, stream>>>(proto, coef, sel_anchor, crop, maskbuf);
    k_resize<<<B_N * MAXOBJ * 8, 256, 0, stream>>>(maskbuf, sel_valid, out);
}

// Round 4
// 208.178 us; speedup vs baseline: 6.3548x; 1.0193x over previous
//
#include <hip/hip_runtime.h>
#include <math.h>

#define A_N     18525
#define A_PAD   18528          // padded row stride (uint4-aligned)
#define B_N     2
#define NCLS    81
#define FG      80
#define TOPN    200
#define MAXOBJ  100
#define PROTO_N 136
#define OUT_N   544
#define COEF_N  32
#define FLATN   (FG*TOPN)      // 16000
#define MIN_SCORE 0.05f
#define NMS_T   0.5f
#define MASK_ELEMS ((size_t)B_N*MAXOBJ*OUT_N*OUT_N)  // 59,187,200

#define ORD_NEG1 0x407FFFFFu   // ordf(-1.0f)
#define ORD_NINF 0x007FFFFFu   // ordf(-inf)
#define HS 17                  // whist stride (16 waves + 1, bank-friendly)

// monotone float<->uint order map (no NaNs in our data)
__device__ __forceinline__ uint32_t ordf(float x) {
    uint32_t u = __float_as_uint(x);
    return (u & 0x80000000u) ? ~u : (u | 0x80000000u);
}
__device__ __forceinline__ float unordf(uint32_t u) {
    return (u & 0x80000000u) ? __uint_as_float(u & 0x7FFFFFFFu)
                             : __uint_as_float(~u);
}

// ---------------------------------------------------------------------------
// Exact top-NSEL select over NELEM ordered-uint values.
// Composite key (value-desc, index-asc, all distinct):
//   K(i) = (vo[i] << 32) | (0xFFFFFFFF - i)
// MSD radix (8-bit digits), per-wave transposed histograms, single-wave
// (wave 0, shfl-only) suffix-scan + boundary detect, register bitmasks for
// alive/selected. SKIP = dominant exact value counted via wave ballot-reduce
// (one atomic per wave) instead of per-element atomics.
// Result: list[0..NSEL) filled with the selected keys in ARBITRARY order.
// ---------------------------------------------------------------------------
template<int NELEM, int NTH, int NW, int NSEL>
__device__ void topk_select(const uint32_t* __restrict__ vo, uint32_t* whist,
                            uint32_t* tot, unsigned long long* list, int* ctrl,
                            int tid, uint32_t SKIP)
{
    unsigned long long alive, sel = 0ull;
    int nown = (tid < NELEM) ? ((NELEM - 1 - tid) / NTH + 1) : 0;
    alive = (nown >= 64) ? ~0ull : ((1ull << nown) - 1ull);
    if (tid == 0) { ctrl[0] = NSEL; ctrl[3] = 0; }
    int wid = tid >> 6, lane = tid & 63;
    __syncthreads();

    for (int p = 7; p >= 0; --p) {
        for (int i = tid; i < 256 * HS; i += NTH) whist[i] = 0u;
        __syncthreads();
        bool useSkip = (p >= 4);
        uint32_t dskip = useSkip ? ((SKIP >> (8 * p - 32)) & 255u) : 0u;
        uint32_t scnt = 0;
        {
            int j = 0;
            for (int i = tid; i < NELEM; i += NTH, ++j) {
                if ((alive >> j) & 1ull) {
                    uint32_t v = vo[i];
                    if (useSkip && v == SKIP) { scnt++; continue; }
                    unsigned long long K =
                        ((unsigned long long)v << 32) | (0xFFFFFFFFu - (uint32_t)i);
                    uint32_t d = (uint32_t)(K >> (8 * p)) & 255u;
                    atomicAdd(&whist[d * HS + wid], 1u);
                }
            }
        }
        if (useSkip) {
            #pragma unroll
            for (int off = 32; off > 0; off >>= 1) {
                uint32_t o = __shfl_down(scnt, off);
                if (lane + off < 64) scnt += o;
            }
            if (lane == 0 && scnt) atomicAdd(&whist[dskip * HS + wid], scnt);
        }
        __syncthreads();
        // merge per-wave hists into tot[256] (conflict-free: stride 17)
        if (tid < 256) {
            uint32_t s = 0;
            #pragma unroll
            for (int w = 0; w < NW; ++w) s += whist[tid * HS + w];
            tot[tid] = s;
        }
        __syncthreads();
        // wave 0: suffix scan over 256 buckets + boundary detect (shfl only)
        if (wid == 0) {
            int R = ctrl[0];
            uint4 tt = ((const uint4*)tot)[lane];      // buckets 4l..4l+3
            uint32_t t_[4] = {tt.x, tt.y, tt.z, tt.w};
            uint32_t s_[4];
            uint32_t lsum = 0;
            #pragma unroll
            for (int q = 3; q >= 0; --q) { lsum += t_[q]; s_[q] = lsum; }
            uint32_t suf = lsum;
            #pragma unroll
            for (int off = 1; off < 64; off <<= 1) {
                uint32_t o = __shfl_down(suf, off);
                if (lane + off < 64) suf += o;
            }
            uint32_t above = suf - lsum;               // sum over lanes > l
            #pragma unroll
            for (int q = 0; q < 4; ++q) {
                uint32_t sInc = above + s_[q];
                uint32_t sAb  = sInc - t_[q];
                if (sInc >= (uint32_t)R && sAb < (uint32_t)R) {
                    int Rb = R - (int)sAb;
                    ctrl[0] = Rb;
                    ctrl[1] = lane * 4 + q;
                    ctrl[2] = (t_[q] == (uint32_t)Rb) ? 1 : 0;
                }
            }
        }
        __syncthreads();
        int bnd  = ctrl[1];
        int done = ctrl[2];
        {
            int j = 0;
            for (int i = tid; i < NELEM; i += NTH, ++j) {
                if ((alive >> j) & 1ull) {
                    unsigned long long K =
                        ((unsigned long long)vo[i] << 32) | (0xFFFFFFFFu - (uint32_t)i);
                    uint32_t d = (uint32_t)(K >> (8 * p)) & 255u;
                    if (d > (uint32_t)bnd || (done && d == (uint32_t)bnd)) {
                        sel |= 1ull << j; alive &= ~(1ull << j);
                    } else if (d < (uint32_t)bnd) {
                        alive &= ~(1ull << j);
                    }
                }
            }
        }
        __syncthreads();
        if (done) break;   // keys distinct -> guaranteed by p==0
    }

    // compact exactly NSEL selected keys (unordered)
    {
        int j = 0;
        for (int i = tid; i < NELEM; i += NTH, ++j) {
            if ((sel >> j) & 1ull) {
                int pos = atomicAdd(&ctrl[3], 1);
                list[pos] = ((unsigned long long)vo[i] << 32) | (0xFFFFFFFFu - (uint32_t)i);
            }
        }
    }
    __syncthreads();
}

// ---------------------------------------------------------------------------
// Kernel 1: softmax + anchor-valid mask + box decode. Row cached in registers.
// S[b][c][a] (stride A_PAD) = ordered uint of (valid ? score : -1.0f)
// ---------------------------------------------------------------------------
__global__ __launch_bounds__(256) void k_decode(
    const float* __restrict__ cls, const float* __restrict__ boxd,
    const float* __restrict__ anchors,
    uint32_t* __restrict__ S, float* __restrict__ boxes)
{
    int idx = blockIdx.x * 256 + threadIdx.x;
    // pad writers (rows have 3 pad entries each; value 0 ranks below everything)
    if (idx < B_N * FG * 3) {
        int row = idx / 3, j = idx - row * 3;
        S[(size_t)row * A_PAD + A_N + j] = 0u;
    }
    if (idx >= B_N * A_N) return;
    int b = idx / A_N, a = idx - b * A_N;
    const float* cl = cls + (size_t)idx * NCLS;

    float r[NCLS];
    #pragma unroll
    for (int i = 0; i < NCLS; ++i) r[i] = cl[i];
    float mx = r[0];
    #pragma unroll
    for (int i = 1; i < NCLS; ++i) mx = fmaxf(mx, r[i]);
    float sum = 0.0f, mfg = 0.0f;
    #pragma unroll
    for (int i = 0; i < NCLS; ++i) {
        float e = expf(r[i] - mx);
        sum += e;
        r[i] = e;
        if (i > 0) mfg = fmaxf(mfg, e);
    }
    float inv = 1.0f / sum;
    int valid = (mfg * inv) > MIN_SCORE;  // strict >

    #pragma unroll
    for (int c = 0; c < FG; ++c) {
        float s = r[c + 1] * inv;
        S[((size_t)b * FG + c) * A_PAD + a] = valid ? ordf(s) : ORD_NEG1;
    }

    const float* an = anchors + (size_t)a * 4;
    const float* bd = boxd + (size_t)idx * 4;
    float aw = an[2], ah = an[3];
    float cx = an[0] + bd[0] * 0.1f * aw;
    float cy = an[1] + bd[1] * 0.1f * ah;
    float w  = aw * expf(bd[2] * 0.2f);
    float h  = ah * expf(bd[3] * 0.2f);
    float x1 = cx - w * 0.5f, y1 = cy - h * 0.5f;
    float x2 = x1 + w,        y2 = y1 + h;
    x1 = fminf(fmaxf(x1, 0.0f), 1.0f);
    y1 = fminf(fmaxf(y1, 0.0f), 1.0f);
    x2 = fminf(fmaxf(x2, 0.0f), 1.0f);
    y2 = fminf(fmaxf(y2, 0.0f), 1.0f);
    float* bo = boxes + (size_t)idx * 4;
    bo[0] = x1; bo[1] = y1; bo[2] = x2; bo[3] = y2;
}

// ---------------------------------------------------------------------------
// Kernel 2: per-(b,c) exact top-200 via radix select + rank-compare write-out.
// LDS: vo[74112B] | list[1600B] | whist[17408B] | tot[1024B] | ctrl[16B]
// ---------------------------------------------------------------------------
#define TOPK_NTH 1024
#define TOPK_NW  (TOPK_NTH/64)
#define TOPK_LDS (A_PAD*4 + TOPN*8 + 256*HS*4 + 256*4 + 16)
__global__ __launch_bounds__(TOPK_NTH) void k_topk(
    const uint32_t* __restrict__ S, int* __restrict__ det_idx,
    float* __restrict__ det_score)
{
    extern __shared__ unsigned char smem[];
    uint32_t* vo = (uint32_t*)smem;
    unsigned long long* list = (unsigned long long*)(smem + A_PAD*4);
    uint32_t* whist = (uint32_t*)(smem + A_PAD*4 + TOPN*8);
    uint32_t* tot   = whist + 256*HS;
    int*      ctrl  = (int*)(tot + 256);

    int bc = blockIdx.x;                  // b*FG + c
    int tid = threadIdx.x;
    const uint4* row4 = (const uint4*)(S + (size_t)bc * A_PAD);
    for (int i = tid; i < A_PAD/4; i += TOPK_NTH) ((uint4*)vo)[i] = row4[i];
    __syncthreads();

    topk_select<A_PAD, TOPK_NTH, TOPK_NW, TOPN>(vo, whist, tot, list, ctrl, tid, ORD_NEG1);

    // rank = #selected keys greater; unique ranks reproduce stable argsort order
    if (tid < TOPN) {
        unsigned long long a = list[tid];
        int r = 0;
        for (int s = 0; s < TOPN; ++s) r += (list[s] > a) ? 1 : 0;
        det_idx[bc * TOPN + r]   = (int)(0xFFFFFFFFu - (uint32_t)a);
        det_score[bc * TOPN + r] = unordf((uint32_t)(a >> 32));
    }
}

// ---------------------------------------------------------------------------
// Kernel 3: fast NMS per (b,c). flat_ord = keep ? ordf(score) : ordf(-inf)
// ---------------------------------------------------------------------------
__global__ __launch_bounds__(256) void k_nms(
    const float* __restrict__ boxes, const int* __restrict__ det_idx,
    const float* __restrict__ det_score, uint32_t* __restrict__ flat)
{
    __shared__ float bx1[TOPN], by1[TOPN], bx2[TOPN], by2[TOPN], ar[TOPN], sc[TOPN];
    __shared__ int dv[TOPN];
    int bc = blockIdx.x;
    int b = bc / FG, c = bc - b * FG;
    int tid = threadIdx.x;
    if (tid < TOPN) {
        int a = det_idx[bc * TOPN + tid];
        const float* bo = boxes + ((size_t)b * A_N + a) * 4;
        float x1 = bo[0], y1 = bo[1], x2 = bo[2], y2 = bo[3];
        bx1[tid] = x1; by1[tid] = y1; bx2[tid] = x2; by2[tid] = y2;
        ar[tid] = (x2 - x1) * (y2 - y1);
        float s = det_score[bc * TOPN + tid];
        sc[tid] = s;
        dv[tid] = (s > -0.5f) ? 1 : 0;   // invalid anchors stored as exactly -1.0
    }
    __syncthreads();
    if (tid < TOPN) {
        float x1 = bx1[tid], y1 = by1[tid], x2 = bx2[tid], y2 = by2[tid];
        float aj = ar[tid];
        bool sup = false;
        for (int i = 0; i < tid; ++i) {
            float iw = fmaxf(fminf(bx2[i], x2) - fmaxf(bx1[i], x1), 0.0f);
            float ih = fmaxf(fminf(by2[i], y2) - fmaxf(by1[i], y1), 0.0f);
            float inter = iw * ih;
            float iou = inter / (ar[i] + aj - inter);   // may be NaN (0/0)
            // reference: iou * det_valid[i] (NaN survives *0), keep = max <= T
            bool bad = dv[i] ? !(iou <= NMS_T) : isnan(iou);
            if (bad) sup = true;
        }
        bool keep = dv[tid] && !sup;
        flat[(size_t)b * FLATN + c * TOPN + tid] = keep ? ordf(sc[tid]) : ORD_NINF;
    }
}

// ---------------------------------------------------------------------------
// Kernel 4: global top-100 per batch via radix select; rank-indexed epilogue.
// LDS: vo[64000B] | list[800B] | whist[17408B] | tot[1024B] | ctrl[16B]
// ---------------------------------------------------------------------------
#define T100_NTH 1024
#define T100_NW  (T100_NTH/64)
#define TOP100_LDS (FLATN*4 + MAXOBJ*8 + 256*HS*4 + 256*4 + 16)
__global__ __launch_bounds__(T100_NTH) void k_top100(
    const uint32_t* __restrict__ flat, const int* __restrict__ det_idx,
    const float* __restrict__ boxes,
    float* __restrict__ lab, float* __restrict__ sco, float* __restrict__ va,
    int* __restrict__ sel_anchor, int* __restrict__ sel_valid,
    float* __restrict__ crop)
{
    extern __shared__ unsigned char smem[];
    uint32_t* vo = (uint32_t*)smem;
    unsigned long long* list = (unsigned long long*)(smem + FLATN*4);
    uint32_t* whist = (uint32_t*)(smem + FLATN*4 + MAXOBJ*8);
    uint32_t* tot   = whist + 256*HS;
    int*      ctrl  = (int*)(tot + 256);

    int b = blockIdx.x;
    int tid = threadIdx.x;
    const uint4* f4 = (const uint4*)(flat + (size_t)b * FLATN);
    for (int i = tid; i < FLATN/4; i += T100_NTH) ((uint4*)vo)[i] = f4[i];
    __syncthreads();

    topk_select<FLATN, T100_NTH, T100_NW, MAXOBJ>(vo, whist, tot, list, ctrl, tid, ORD_NINF);

    if (tid < MAXOBJ) {
        unsigned long long K = list[tid];
        int r = 0;
        for (int s = 0; s < MAXOBJ; ++s) r += (list[s] > K) ? 1 : 0;
        int fi = (int)(0xFFFFFFFFu - (uint32_t)K);
        float fv = unordf((uint32_t)(K >> 32));
        int valid = (fv > -1e37f) ? 1 : 0;          // isfinite (scores in (0,1])
        int c = fi / TOPN, t = fi - c * TOPN;
        int anchor = det_idx[((size_t)b * FG + c) * TOPN + t];
        lab[b * MAXOBJ + r] = valid ? (float)c : -1.0f;
        sco[b * MAXOBJ + r] = valid ? fv : 0.0f;
        va [b * MAXOBJ + r] = valid ? 1.0f : 0.0f;
        sel_anchor[b * MAXOBJ + r] = anchor;
        sel_valid [b * MAXOBJ + r] = valid;
        const float* bo = boxes + ((size_t)b * A_N + anchor) * 4;
        float xlo = fminf(bo[0], bo[2]), xhi = fmaxf(bo[0], bo[2]);
        float ylo = fminf(bo[1], bo[3]), yhi = fmaxf(bo[1], bo[3]);
        float* cr = crop + ((size_t)b * MAXOBJ + r) * 4;
        cr[0] = fmaxf(xlo * (float)PROTO_N - 1.0f, 0.0f);
        cr[1] = fminf(xhi * (float)PROTO_N + 1.0f, (float)PROTO_N);
        cr[2] = fmaxf(ylo * (float)PROTO_N - 1.0f, 0.0f);
        cr[3] = fminf(yhi * (float)PROTO_N + 1.0f, (float)PROTO_N);
    }
}

// ---------------------------------------------------------------------------
// Kernel 5: proto @ coef^T -> sigmoid -> crop, at proto resolution.
// Chunked (n, x-quad) units; coefficient vector cached in registers.
// ---------------------------------------------------------------------------
__global__ __launch_bounds__(256) void k_mask(
    const float* __restrict__ proto, const float* __restrict__ coefs,
    const int* __restrict__ sel_anchor, const float* __restrict__ crop,
    float* __restrict__ maskbuf)
{
    __shared__ float prow[PROTO_N * 33];
    __shared__ float cf[MAXOBJ * COEF_N];
    __shared__ float cb[MAXOBJ][4];
    int blk = blockIdx.x;
    int b = blk / PROTO_N, y = blk - b * PROTO_N;
    int tid = threadIdx.x;

    const float* pr = proto + ((size_t)(b * PROTO_N + y) * PROTO_N) * COEF_N;
    for (int i = tid; i < PROTO_N * COEF_N; i += 256) {
        int x = i >> 5, c = i & 31;
        prow[x * 33 + c] = pr[i];
    }
    for (int i = tid; i < MAXOBJ * COEF_N; i += 256) {
        int n = i >> 5;
        cf[i] = coefs[((size_t)b * A_N + sel_anchor[b * MAXOBJ + n]) * COEF_N + (i & 31)];
    }
    if (tid < MAXOBJ) {
        const float* cr = crop + ((size_t)b * MAXOBJ + tid) * 4;
        cb[tid][0] = cr[0]; cb[tid][1] = cr[1]; cb[tid][2] = cr[2]; cb[tid][3] = cr[3];
    }
    __syncthreads();

    const int QPR = PROTO_N / 4;         // 34 x-quads per row
    const int UNITS = MAXOBJ * QPR;      // 3400
    float yf = (float)y;
    float cp[COEF_N];
    int curn = -1;
    bool rowOK = false;
    float c0 = 0, c1 = 0;
    int u0 = tid * 14;                   // contiguous chunk: cp reuse across units
    for (int s = 0; s < 14; ++s) {
        int u = u0 + s;
        if (u >= UNITS) break;
        int n = u / QPR, xq = u - n * QPR;
        if (n != curn) {
            curn = n;
            #pragma unroll
            for (int c = 0; c < COEF_N; ++c) cp[c] = cf[n * COEF_N + c];
            rowOK = (yf >= cb[n][2]) && (yf < cb[n][3]);
            c0 = cb[n][0]; c1 = cb[n][1];
        }
        int x0 = xq * 4;
        float4 o;
        #pragma unroll
        for (int j = 0; j < 4; ++j) {
            int x = x0 + j;
            const float* pp = prow + x * 33;
            float d = 0.0f;
            #pragma unroll
            for (int c = 0; c < COEF_N; ++c) d = fmaf(pp[c], cp[c], d);
            float m = 1.0f / (1.0f + expf(-d));
            float xf = (float)x;
            bool keep = rowOK && (xf >= c0) && (xf < c1);
            ((float*)&o)[j] = keep ? m : 0.0f;
        }
        *(float4*)&maskbuf[(((size_t)b * MAXOBJ + n) * PROTO_N + y) * PROTO_N + x0] = o;
    }
}

// ---------------------------------------------------------------------------
// Kernel 6: bilinear x4 upsample + valid gate + >0.5, phase-decomposed,
// float4 loads/stores.
// ---------------------------------------------------------------------------
__global__ __launch_bounds__(256) void k_resize(
    const float* __restrict__ maskbuf, const int* __restrict__ sel_valid,
    float* __restrict__ out)
{
    __shared__ float src[19 * PROTO_N];
    int blk = blockIdx.x;            // B*100*8
    int tile = blk & 7;
    int bn = blk >> 3;               // b*100+n
    int tid = threadIdx.x;

    int oy0 = tile * 68;
    float sy0 = (oy0 + 0.5f) * 0.25f - 0.5f;
    float sy1 = (oy0 + 67 + 0.5f) * 0.25f - 0.5f;
    int iy_lo = max((int)floorf(sy0), 0);
    int iy_hi = min((int)floorf(sy1) + 1, PROTO_N - 1);
    int nrows = iy_hi - iy_lo + 1;

    const float4* mb4 = (const float4*)(maskbuf + ((size_t)bn * PROTO_N + iy_lo) * PROTO_N);
    for (int i = tid; i < nrows * (PROTO_N/4); i += 256) ((float4*)src)[i] = mb4[i];
    int val = sel_valid[bn];
    __syncthreads();

    const int QPR = PROTO_N;             // 136 x-quads per output row (544/4)
    const int UNITS = 68 * QPR;          // 9248
    for (int u = tid; u < UNITS; u += 256) {
        int oyl = u / QPR, xq = u - oyl * QPR;
        int oy = oy0 + oyl;
        float sy = (oy + 0.5f) * 0.25f - 0.5f;
        int iy0 = (int)floorf(sy);
        float fy = sy - (float)iy0;
        const float* r0 = src + (min(max(iy0,     0), PROTO_N - 1) - iy_lo) * PROTO_N;
        const float* r1 = src + (min(max(iy0 + 1, 0), PROTO_N - 1) - iy_lo) * PROTO_N;
        // ox = 4*xq + {0,1,2,3}: taps (k-1,k) fx={0.625,0.875}; (k,k+1) fx={0.125,0.375}
        int km = (xq == 0) ? 0 : xq - 1;
        int kp = (xq == PROTO_N - 1) ? PROTO_N - 1 : xq + 1;
        float a0 = r0[km], b0 = r0[xq], cc0 = r0[kp];
        float a1 = r1[km], b1 = r1[xq], cc1 = r1[kp];
        float h00 = a0 * 0.375f + b0 * 0.625f;
        float h01 = a0 * 0.125f + b0 * 0.875f;
        float h02 = b0 * 0.875f + cc0 * 0.125f;
        float h03 = b0 * 0.625f + cc0 * 0.375f;
        float h10 = a1 * 0.375f + b1 * 0.625f;
        float h11 = a1 * 0.125f + b1 * 0.875f;
        float h12 = b1 * 0.875f + cc1 * 0.125f;
        float h13 = b1 * 0.625f + cc1 * 0.375f;
        float g = 1.0f - fy;
        float m0 = h00 * g + h10 * fy;
        float m1 = h01 * g + h11 * fy;
        float m2 = h02 * g + h12 * fy;
        float m3 = h03 * g + h13 * fy;
        float4 o;
        o.x = (val && m0 > 0.5f) ? 1.0f : 0.0f;
        o.y = (val && m1 > 0.5f) ? 1.0f : 0.0f;
        o.z = (val && m2 > 0.5f) ? 1.0f : 0.0f;
        o.w = (val && m3 > 0.5f) ? 1.0f : 0.0f;
        *(float4*)&out[((size_t)bn * OUT_N + oy) * OUT_N + 4 * xq] = o;
    }
}

// ---------------------------------------------------------------------------
extern "C" void kernel_launch(void* const* d_in, const int* in_sizes, int n_in,
                              void* d_out, int out_size, void* d_ws, size_t ws_size,
                              hipStream_t stream)
{
    const float* cls   = (const float*)d_in[0];
    const float* boxd  = (const float*)d_in[1];
    const float* coef  = (const float*)d_in[2];
    const float* proto = (const float*)d_in[3];
    const float* anch  = (const float*)d_in[4];
    float* out = (float*)d_out;

    char* ws = (char*)d_ws;
    size_t off = 0;
    auto alloc = [&](size_t bytes) -> void* {
        void* p = ws + off;
        off += (bytes + 255) & ~(size_t)255;
        return p;
    };
    uint32_t* S      = (uint32_t*)alloc((size_t)B_N * FG * A_PAD * 4);
    float* boxes     = (float*)alloc((size_t)B_N * A_N * 4 * 4);
    int*   det_idx   = (int*)  alloc((size_t)B_N * FG * TOPN * 4);
    float* det_score = (float*)alloc((size_t)B_N * FG * TOPN * 4);
    uint32_t* flat   = (uint32_t*)alloc((size_t)B_N * FLATN * 4);
    int*   sel_anchor= (int*)  alloc((size_t)B_N * MAXOBJ * 4);
    int*   sel_valid = (int*)  alloc((size_t)B_N * MAXOBJ * 4);
    float* crop      = (float*)alloc((size_t)B_N * MAXOBJ * 4 * 4);
    float* maskbuf   = (float*)alloc((size_t)B_N * MAXOBJ * PROTO_N * PROTO_N * 4);
    (void)ws_size; (void)in_sizes; (void)n_in; (void)out_size;

    float* lab = out + MASK_ELEMS;
    float* sco = lab + B_N * MAXOBJ;
    float* va  = sco + B_N * MAXOBJ;

    k_decode<<<(B_N * A_N + 255) / 256, 256, 0, stream>>>(cls, boxd, anch, S, boxes);
    k_topk<<<B_N * FG, TOPK_NTH, TOPK_LDS, stream>>>(S, det_idx, det_score);
    k_nms<<<B_N * FG, 256, 0, stream>>>(boxes, det_idx, det_score, flat);
    k_top100<<<B_N, T100_NTH, TOP100_LDS, stream>>>(flat, det_idx, boxes, lab, sco, va,
                                                    sel_anchor, sel_valid, crop);
    k_mask<<<B_N * PROTO_N, 256, 0, stream>>>(proto, coef, sel_anchor, crop, maskbuf);
    k_resize<<<B_N * MAXOBJ * 8, 256, 0, stream>>>(maskbuf, sel_valid, out);
}

// Round 5
// 207.456 us; speedup vs baseline: 6.3769x; 1.0035x over previous
//
#include <hip/hip_runtime.h>
#include <math.h>

#define A_N     18525
#define A_PAD   18528          // padded row stride (uint4-aligned)
#define B_N     2
#define NCLS    81
#define FG      80
#define TOPN    200
#define MAXOBJ  100
#define PROTO_N 136
#define OUT_N   544
#define COEF_N  32
#define FLATN   (FG*TOPN)      // 16000
#define MIN_SCORE 0.05f
#define NMS_T   0.5f
#define MASK_ELEMS ((size_t)B_N*MAXOBJ*OUT_N*OUT_N)  // 59,187,200

#define ORD_NEG1 0x407FFFFFu   // ordf(-1.0f)
#define ORD_NINF 0x007FFFFFu   // ordf(-inf)
#define HS 17                  // whist stride (16 waves + 1, bank-friendly)

// monotone float<->uint order map (no NaNs in our data)
__device__ __forceinline__ uint32_t ordf(float x) {
    uint32_t u = __float_as_uint(x);
    return (u & 0x80000000u) ? ~u : (u | 0x80000000u);
}
__device__ __forceinline__ float unordf(uint32_t u) {
    return (u & 0x80000000u) ? __uint_as_float(u & 0x7FFFFFFFu)
                             : __uint_as_float(~u);
}

// ---------------------------------------------------------------------------
// Exact top-NSEL select over NELEM ordered-uint values (see round-3 notes).
// Result: list[0..NSEL) filled with selected keys in ARBITRARY order.
// ---------------------------------------------------------------------------
template<int NELEM, int NTH, int NW, int NSEL>
__device__ void topk_select(const uint32_t* __restrict__ vo, uint32_t* whist,
                            uint32_t* tot, unsigned long long* list, int* ctrl,
                            int tid, uint32_t SKIP)
{
    unsigned long long alive, sel = 0ull;
    int nown = (tid < NELEM) ? ((NELEM - 1 - tid) / NTH + 1) : 0;
    alive = (nown >= 64) ? ~0ull : ((1ull << nown) - 1ull);
    if (tid == 0) { ctrl[0] = NSEL; ctrl[3] = 0; }
    int wid = tid >> 6, lane = tid & 63;
    __syncthreads();

    for (int p = 7; p >= 0; --p) {
        for (int i = tid; i < 256 * HS; i += NTH) whist[i] = 0u;
        __syncthreads();
        bool useSkip = (p >= 4);
        uint32_t dskip = useSkip ? ((SKIP >> (8 * p - 32)) & 255u) : 0u;
        uint32_t scnt = 0;
        {
            int j = 0;
            for (int i = tid; i < NELEM; i += NTH, ++j) {
                if ((alive >> j) & 1ull) {
                    uint32_t v = vo[i];
                    if (useSkip && v == SKIP) { scnt++; continue; }
                    unsigned long long K =
                        ((unsigned long long)v << 32) | (0xFFFFFFFFu - (uint32_t)i);
                    uint32_t d = (uint32_t)(K >> (8 * p)) & 255u;
                    atomicAdd(&whist[d * HS + wid], 1u);
                }
            }
        }
        if (useSkip) {
            #pragma unroll
            for (int off = 32; off > 0; off >>= 1) {
                uint32_t o = __shfl_down(scnt, off);
                if (lane + off < 64) scnt += o;
            }
            if (lane == 0 && scnt) atomicAdd(&whist[dskip * HS + wid], scnt);
        }
        __syncthreads();
        if (tid < 256) {
            uint32_t s = 0;
            #pragma unroll
            for (int w = 0; w < NW; ++w) s += whist[tid * HS + w];
            tot[tid] = s;
        }
        __syncthreads();
        if (wid == 0) {
            int R = ctrl[0];
            uint4 tt = ((const uint4*)tot)[lane];
            uint32_t t_[4] = {tt.x, tt.y, tt.z, tt.w};
            uint32_t s_[4];
            uint32_t lsum = 0;
            #pragma unroll
            for (int q = 3; q >= 0; --q) { lsum += t_[q]; s_[q] = lsum; }
            uint32_t suf = lsum;
            #pragma unroll
            for (int off = 1; off < 64; off <<= 1) {
                uint32_t o = __shfl_down(suf, off);
                if (lane + off < 64) suf += o;
            }
            uint32_t above = suf - lsum;
            #pragma unroll
            for (int q = 0; q < 4; ++q) {
                uint32_t sInc = above + s_[q];
                uint32_t sAb  = sInc - t_[q];
                if (sInc >= (uint32_t)R && sAb < (uint32_t)R) {
                    int Rb = R - (int)sAb;
                    ctrl[0] = Rb;
                    ctrl[1] = lane * 4 + q;
                    ctrl[2] = (t_[q] == (uint32_t)Rb) ? 1 : 0;
                }
            }
        }
        __syncthreads();
        int bnd  = ctrl[1];
        int done = ctrl[2];
        {
            int j = 0;
            for (int i = tid; i < NELEM; i += NTH, ++j) {
                if ((alive >> j) & 1ull) {
                    unsigned long long K =
                        ((unsigned long long)vo[i] << 32) | (0xFFFFFFFFu - (uint32_t)i);
                    uint32_t d = (uint32_t)(K >> (8 * p)) & 255u;
                    if (d > (uint32_t)bnd || (done && d == (uint32_t)bnd)) {
                        sel |= 1ull << j; alive &= ~(1ull << j);
                    } else if (d < (uint32_t)bnd) {
                        alive &= ~(1ull << j);
                    }
                }
            }
        }
        __syncthreads();
        if (done) break;   // keys distinct -> guaranteed by p==0
    }

    {
        int j = 0;
        for (int i = tid; i < NELEM; i += NTH, ++j) {
            if ((sel >> j) & 1ull) {
                int pos = atomicAdd(&ctrl[3], 1);
                list[pos] = ((unsigned long long)vo[i] << 32) | (0xFFFFFFFFu - (uint32_t)i);
            }
        }
    }
    __syncthreads();
}

// ---------------------------------------------------------------------------
// Kernel 1: softmax + anchor-valid mask + box decode (bit-exact path).
// ---------------------------------------------------------------------------
__global__ __launch_bounds__(256) void k_decode(
    const float* __restrict__ cls, const float* __restrict__ boxd,
    const float* __restrict__ anchors,
    uint32_t* __restrict__ S, float* __restrict__ boxes)
{
    int idx = blockIdx.x * 256 + threadIdx.x;
    if (idx < B_N * FG * 3) {          // pad entries rank below everything
        int row = idx / 3, j = idx - row * 3;
        S[(size_t)row * A_PAD + A_N + j] = 0u;
    }
    if (idx >= B_N * A_N) return;
    int b = idx / A_N, a = idx - b * A_N;
    const float* cl = cls + (size_t)idx * NCLS;

    float r[NCLS];
    #pragma unroll
    for (int i = 0; i < NCLS; ++i) r[i] = cl[i];
    float mx = r[0];
    #pragma unroll
    for (int i = 1; i < NCLS; ++i) mx = fmaxf(mx, r[i]);
    float sum = 0.0f, mfg = 0.0f;
    #pragma unroll
    for (int i = 0; i < NCLS; ++i) {
        float e = expf(r[i] - mx);
        sum += e;
        r[i] = e;
        if (i > 0) mfg = fmaxf(mfg, e);
    }
    float inv = 1.0f / sum;
    int valid = (mfg * inv) > MIN_SCORE;  // strict >

    #pragma unroll
    for (int c = 0; c < FG; ++c) {
        float s = r[c + 1] * inv;
        S[((size_t)b * FG + c) * A_PAD + a] = valid ? ordf(s) : ORD_NEG1;
    }

    const float* an = anchors + (size_t)a * 4;
    const float* bd = boxd + (size_t)idx * 4;
    float aw = an[2], ah = an[3];
    float cx = an[0] + bd[0] * 0.1f * aw;
    float cy = an[1] + bd[1] * 0.1f * ah;
    float w  = aw * expf(bd[2] * 0.2f);
    float h  = ah * expf(bd[3] * 0.2f);
    float x1 = cx - w * 0.5f, y1 = cy - h * 0.5f;
    float x2 = x1 + w,        y2 = y1 + h;
    x1 = fminf(fmaxf(x1, 0.0f), 1.0f);
    y1 = fminf(fmaxf(y1, 0.0f), 1.0f);
    x2 = fminf(fmaxf(x2, 0.0f), 1.0f);
    y2 = fminf(fmaxf(y2, 0.0f), 1.0f);
    float* bo = boxes + (size_t)idx * 4;
    bo[0] = x1; bo[1] = y1; bo[2] = x2; bo[3] = y2;
}

// ---------------------------------------------------------------------------
// Kernel 2: per-(b,c) top-200 (radix select + rank order) FUSED with fast-NMS.
// Emits det_idx (anchor per slot) and flat (keep ? ord(score) : ord(-inf)).
// LDS: vo[74112B] | list[1600B] | whist[17408B incl. NMS arrays] | tot | ctrl
// ---------------------------------------------------------------------------
#define TOPK_NTH 1024
#define TOPK_NW  (TOPK_NTH/64)
#define TOPK_LDS (A_PAD*4 + TOPN*8 + 256*HS*4 + 256*4 + 16)
__global__ __launch_bounds__(TOPK_NTH) void k_topk_nms(
    const uint32_t* __restrict__ S, const float* __restrict__ boxes,
    int* __restrict__ det_idx, uint32_t* __restrict__ flat)
{
    extern __shared__ unsigned char smem[];
    uint32_t* vo = (uint32_t*)smem;
    unsigned long long* list = (unsigned long long*)(smem + A_PAD*4);
    uint32_t* whist = (uint32_t*)(smem + A_PAD*4 + TOPN*8);
    uint32_t* tot   = whist + 256*HS;
    int*      ctrl  = (int*)(tot + 256);
    // NMS scratch aliased onto whist region (free after select)
    float* sx1 = (float*)whist;
    float* sy1 = sx1 + TOPN;
    float* sx2 = sy1 + TOPN;
    float* sy2 = sx2 + TOPN;
    float* sar = sy2 + TOPN;
    float* ssc = sar + TOPN;
    int*   sid = (int*)(ssc + TOPN);

    int bc = blockIdx.x;                  // b*FG + c
    int b = bc / FG, c = bc - b * FG;
    int tid = threadIdx.x;
    const uint4* row4 = (const uint4*)(S + (size_t)bc * A_PAD);
    for (int i = tid; i < A_PAD/4; i += TOPK_NTH) ((uint4*)vo)[i] = row4[i];
    __syncthreads();

    topk_select<A_PAD, TOPK_NTH, TOPK_NW, TOPN>(vo, whist, tot, list, ctrl, tid, ORD_NEG1);

    // rank-scatter into sorted order (unique ranks = stable argsort order)
    if (tid < TOPN) {
        unsigned long long a = list[tid];
        int r = 0;
        for (int s = 0; s < TOPN; ++s) r += (list[s] > a) ? 1 : 0;
        sid[r] = (int)(0xFFFFFFFFu - (uint32_t)a);
        ssc[r] = unordf((uint32_t)(a >> 32));
    }
    __syncthreads();

    // load boxes for the 200 dets
    if (tid < TOPN) {
        int a = sid[tid];
        float4 bo = *(const float4*)(boxes + ((size_t)b * A_N + a) * 4);
        sx1[tid] = bo.x; sy1[tid] = bo.y; sx2[tid] = bo.z; sy2[tid] = bo.w;
        sar[tid] = (bo.z - bo.x) * (bo.w - bo.y);
    }
    __syncthreads();

    if (tid < TOPN) {
        float x1 = sx1[tid], y1 = sy1[tid], x2 = sx2[tid], y2 = sy2[tid];
        float aj = sar[tid];
        float s = ssc[tid];
        int dvj = (s > -0.5f) ? 1 : 0;    // invalid anchors are exactly -1.0
        bool sup = false;
        for (int i = 0; i < tid; ++i) {
            float iw = fmaxf(fminf(sx2[i], x2) - fmaxf(sx1[i], x1), 0.0f);
            float ih = fmaxf(fminf(sy2[i], y2) - fmaxf(sy1[i], y1), 0.0f);
            float inter = iw * ih;
            float iou = inter / (sar[i] + aj - inter);   // may be NaN (0/0)
            int dvi = (ssc[i] > -0.5f) ? 1 : 0;
            // reference: iou * det_valid[i] (NaN survives *0), keep = max <= T
            bool bad = dvi ? !(iou <= NMS_T) : isnan(iou);
            if (bad) sup = true;
        }
        bool keep = dvj && !sup;
        det_idx[bc * TOPN + tid] = sid[tid];
        flat[(size_t)b * FLATN + c * TOPN + tid] = keep ? ordf(s) : ORD_NINF;
    }
}

// ---------------------------------------------------------------------------
// Kernel 3: global top-100 per batch via radix select; rank-indexed epilogue.
// ---------------------------------------------------------------------------
#define T100_NTH 1024
#define T100_NW  (T100_NTH/64)
#define TOP100_LDS (FLATN*4 + MAXOBJ*8 + 256*HS*4 + 256*4 + 16)
__global__ __launch_bounds__(T100_NTH) void k_top100(
    const uint32_t* __restrict__ flat, const int* __restrict__ det_idx,
    const float* __restrict__ boxes,
    float* __restrict__ lab, float* __restrict__ sco, float* __restrict__ va,
    int* __restrict__ sel_anchor, int* __restrict__ sel_valid,
    float* __restrict__ crop)
{
    extern __shared__ unsigned char smem[];
    uint32_t* vo = (uint32_t*)smem;
    unsigned long long* list = (unsigned long long*)(smem + FLATN*4);
    uint32_t* whist = (uint32_t*)(smem + FLATN*4 + MAXOBJ*8);
    uint32_t* tot   = whist + 256*HS;
    int*      ctrl  = (int*)(tot + 256);

    int b = blockIdx.x;
    int tid = threadIdx.x;
    const uint4* f4 = (const uint4*)(flat + (size_t)b * FLATN);
    for (int i = tid; i < FLATN/4; i += T100_NTH) ((uint4*)vo)[i] = f4[i];
    __syncthreads();

    topk_select<FLATN, T100_NTH, T100_NW, MAXOBJ>(vo, whist, tot, list, ctrl, tid, ORD_NINF);

    if (tid < MAXOBJ) {
        unsigned long long K = list[tid];
        int r = 0;
        for (int s = 0; s < MAXOBJ; ++s) r += (list[s] > K) ? 1 : 0;
        int fi = (int)(0xFFFFFFFFu - (uint32_t)K);
        float fv = unordf((uint32_t)(K >> 32));
        int valid = (fv > -1e37f) ? 1 : 0;          // isfinite (scores in (0,1])
        int c = fi / TOPN, t = fi - c * TOPN;
        int anchor = det_idx[((size_t)b * FG + c) * TOPN + t];
        lab[b * MAXOBJ + r] = valid ? (float)c : -1.0f;
        sco[b * MAXOBJ + r] = valid ? fv : 0.0f;
        va [b * MAXOBJ + r] = valid ? 1.0f : 0.0f;
        sel_anchor[b * MAXOBJ + r] = anchor;
        sel_valid [b * MAXOBJ + r] = valid;
        const float* bo = boxes + ((size_t)b * A_N + anchor) * 4;
        float xlo = fminf(bo[0], bo[2]), xhi = fmaxf(bo[0], bo[2]);
        float ylo = fminf(bo[1], bo[3]), yhi = fmaxf(bo[1], bo[3]);
        float* cr = crop + ((size_t)b * MAXOBJ + r) * 4;
        cr[0] = fmaxf(xlo * (float)PROTO_N - 1.0f, 0.0f);
        cr[1] = fminf(xhi * (float)PROTO_N + 1.0f, (float)PROTO_N);
        cr[2] = fmaxf(ylo * (float)PROTO_N - 1.0f, 0.0f);
        cr[3] = fminf(yhi * (float)PROTO_N + 1.0f, (float)PROTO_N);
    }
}

// ---------------------------------------------------------------------------
// Kernel 4: proto @ coef^T -> sigmoid -> crop. Thread = one proto pixel:
// proto row in 32 VGPRs (global, coalesced); coef/crop are wave-uniform ->
// scalar loads + SGPR-operand FMAs. No LDS at all.
// ---------------------------------------------------------------------------
__global__ __launch_bounds__(256) void k_mask(
    const float* __restrict__ proto, const float* __restrict__ coefs,
    const int* __restrict__ sel_anchor, const float* __restrict__ crop,
    float* __restrict__ maskbuf)
{
    int pix = blockIdx.x * 256 + threadIdx.x;      // over B*PROTO*PROTO
    if (pix >= B_N * PROTO_N * PROTO_N) return;
    int b = pix / (PROTO_N * PROTO_N);
    int rem = pix - b * (PROTO_N * PROTO_N);
    int y = rem / PROTO_N, x = rem - y * PROTO_N;

    float p[COEF_N];
    const float4* pr = (const float4*)(proto + (size_t)pix * COEF_N);
    #pragma unroll
    for (int q = 0; q < 8; ++q) {
        float4 v = pr[q];
        p[4*q] = v.x; p[4*q+1] = v.y; p[4*q+2] = v.z; p[4*q+3] = v.w;
    }
    float xf = (float)x, yf = (float)y;
    float* outp = maskbuf + ((size_t)b * MAXOBJ * PROTO_N + y) * PROTO_N + x;

    for (int n = 0; n < MAXOBJ; ++n) {
        int anchor = __builtin_amdgcn_readfirstlane(sel_anchor[b * MAXOBJ + n]);
        const float* cp = coefs + ((size_t)b * A_N + anchor) * COEF_N;
        float d = 0.0f;
        #pragma unroll
        for (int c = 0; c < COEF_N; ++c) d = fmaf(p[c], cp[c], d);
        float m = 1.0f / (1.0f + __expf(-d));
        const float* cr = crop + ((size_t)b * MAXOBJ + n) * 4;
        float c0 = cr[0], c1 = cr[1], c2 = cr[2], c3 = cr[3];
        bool keep = (xf >= c0) && (xf < c1) && (yf >= c2) && (yf < c3);
        outp[(size_t)n * PROTO_N * PROTO_N] = keep ? m : 0.0f;
    }
}

// ---------------------------------------------------------------------------
// Kernel 5: bilinear x4 upsample + valid gate + >0.5, phase-decomposed,
// float4 loads/stores.
// ---------------------------------------------------------------------------
__global__ __launch_bounds__(256) void k_resize(
    const float* __restrict__ maskbuf, const int* __restrict__ sel_valid,
    float* __restrict__ out)
{
    __shared__ float src[19 * PROTO_N];
    int blk = blockIdx.x;            // B*100*8
    int tile = blk & 7;
    int bn = blk >> 3;               // b*100+n
    int tid = threadIdx.x;

    int oy0 = tile * 68;
    float sy0 = (oy0 + 0.5f) * 0.25f - 0.5f;
    float sy1 = (oy0 + 67 + 0.5f) * 0.25f - 0.5f;
    int iy_lo = max((int)floorf(sy0), 0);
    int iy_hi = min((int)floorf(sy1) + 1, PROTO_N - 1);
    int nrows = iy_hi - iy_lo + 1;

    const float4* mb4 = (const float4*)(maskbuf + ((size_t)bn * PROTO_N + iy_lo) * PROTO_N);
    for (int i = tid; i < nrows * (PROTO_N/4); i += 256) ((float4*)src)[i] = mb4[i];
    int val = sel_valid[bn];
    __syncthreads();

    const int QPR = PROTO_N;             // 136 x-quads per output row (544/4)
    const int UNITS = 68 * QPR;          // 9248
    for (int u = tid; u < UNITS; u += 256) {
        int oyl = u / QPR, xq = u - oyl * QPR;
        int oy = oy0 + oyl;
        float sy = (oy + 0.5f) * 0.25f - 0.5f;
        int iy0 = (int)floorf(sy);
        float fy = sy - (float)iy0;
        const float* r0 = src + (min(max(iy0,     0), PROTO_N - 1) - iy_lo) * PROTO_N;
        const float* r1 = src + (min(max(iy0 + 1, 0), PROTO_N - 1) - iy_lo) * PROTO_N;
        int km = (xq == 0) ? 0 : xq - 1;
        int kp = (xq == PROTO_N - 1) ? PROTO_N - 1 : xq + 1;
        float a0 = r0[km], b0 = r0[xq], cc0 = r0[kp];
        float a1 = r1[km], b1 = r1[xq], cc1 = r1[kp];
        float h00 = a0 * 0.375f + b0 * 0.625f;
        float h01 = a0 * 0.125f + b0 * 0.875f;
        float h02 = b0 * 0.875f + cc0 * 0.125f;
        float h03 = b0 * 0.625f + cc0 * 0.375f;
        float h10 = a1 * 0.375f + b1 * 0.625f;
        float h11 = a1 * 0.125f + b1 * 0.875f;
        float h12 = b1 * 0.875f + cc1 * 0.125f;
        float h13 = b1 * 0.625f + cc1 * 0.375f;
        float g = 1.0f - fy;
        float m0 = h00 * g + h10 * fy;
        float m1 = h01 * g + h11 * fy;
        float m2 = h02 * g + h12 * fy;
        float m3 = h03 * g + h13 * fy;
        float4 o;
        o.x = (val && m0 > 0.5f) ? 1.0f : 0.0f;
        o.y = (val && m1 > 0.5f) ? 1.0f : 0.0f;
        o.z = (val && m2 > 0.5f) ? 1.0f : 0.0f;
        o.w = (val && m3 > 0.5f) ? 1.0f : 0.0f;
        *(float4*)&out[((size_t)bn * OUT_N + oy) * OUT_N + 4 * xq] = o;
    }
}

// ---------------------------------------------------------------------------
extern "C" void kernel_launch(void* const* d_in, const int* in_sizes, int n_in,
                              void* d_out, int out_size, void* d_ws, size_t ws_size,
                              hipStream_t stream)
{
    const float* cls   = (const float*)d_in[0];
    const float* boxd  = (const float*)d_in[1];
    const float* coef  = (const float*)d_in[2];
    const float* proto = (const float*)d_in[3];
    const float* anch  = (const float*)d_in[4];
    float* out = (float*)d_out;

    char* ws = (char*)d_ws;
    size_t off = 0;
    auto alloc = [&](size_t bytes) -> void* {
        void* p = ws + off;
        off += (bytes + 255) & ~(size_t)255;
        return p;
    };
    uint32_t* S      = (uint32_t*)alloc((size_t)B_N * FG * A_PAD * 4);
    float* boxes     = (float*)alloc((size_t)B_N * A_N * 4 * 4);
    int*   det_idx   = (int*)  alloc((size_t)B_N * FG * TOPN * 4);
    uint32_t* flat   = (uint32_t*)alloc((size_t)B_N * FLATN * 4);
    int*   sel_anchor= (int*)  alloc((size_t)B_N * MAXOBJ * 4);
    int*   sel_valid = (int*)  alloc((size_t)B_N * MAXOBJ * 4);
    float* crop      = (float*)alloc((size_t)B_N * MAXOBJ * 4 * 4);
    float* maskbuf   = (float*)alloc((size_t)B_N * MAXOBJ * PROTO_N * PROTO_N * 4);
    (void)ws_size; (void)in_sizes; (void)n_in; (void)out_size;

    float* lab = out + MASK_ELEMS;
    float* sco = lab + B_N * MAXOBJ;
    float* va  = sco + B_N * MAXOBJ;

    k_decode<<<(B_N * A_N + 255) / 256, 256, 0, stream>>>(cls, boxd, anch, S, boxes);
    k_topk_nms<<<B_N * FG, TOPK_NTH, TOPK_LDS, stream>>>(S, boxes, det_idx, flat);
    k_top100<<<B_N, T100_NTH, TOP100_LDS, stream>>>(flat, det_idx, boxes, lab, sco, va,
                                                    sel_anchor, sel_valid, crop);
    k_mask<<<(B_N * PROTO_N * PROTO_N + 255) / 256, 256, 0, stream>>>(
        proto, coef, sel_anchor, crop, maskbuf);
    k_resize<<<B_N * MAXOBJ * 8, 256, 0, stream>>>(maskbuf, sel_valid, out);
}

// Round 6
// 196.255 us; speedup vs baseline: 6.7409x; 1.0571x over previous
//
#include <hip/hip_runtime.h>
#include <math.h>

#define A_N     18525
#define A_PAD   18528          // padded row stride (uint4-aligned)
#define B_N     2
#define NCLS    81
#define FG      80
#define TOPN    200
#define MAXOBJ  100
#define PROTO_N 136
#define OUT_N   544
#define COEF_N  32
#define FLATN   (FG*TOPN)      // 16000
#define MIN_SCORE 0.05f
#define NMS_T   0.5f
#define MASK_ELEMS ((size_t)B_N*MAXOBJ*OUT_N*OUT_N)  // 59,187,200

#define ORD_NEG1 0x407FFFFFu   // ordf(-1.0f)
#define ORD_NINF 0x007FFFFFu   // ordf(-inf)
#define HS 17                  // whist stride (16 waves + 1, bank-friendly)

// monotone float<->uint order map (no NaNs in our data)
__device__ __forceinline__ uint32_t ordf(float x) {
    uint32_t u = __float_as_uint(x);
    return (u & 0x80000000u) ? ~u : (u | 0x80000000u);
}
__device__ __forceinline__ float unordf(uint32_t u) {
    return (u & 0x80000000u) ? __uint_as_float(u & 0x7FFFFFFFu)
                             : __uint_as_float(~u);
}

// ---------------------------------------------------------------------------
// Exact top-NSEL select over NELEM ordered-uint values (round-3 design).
// Result: list[0..NSEL) filled with selected keys in ARBITRARY order.
// ---------------------------------------------------------------------------
template<int NELEM, int NTH, int NW, int NSEL>
__device__ void topk_select(const uint32_t* __restrict__ vo, uint32_t* whist,
                            uint32_t* tot, unsigned long long* list, int* ctrl,
                            int tid, uint32_t SKIP)
{
    unsigned long long alive, sel = 0ull;
    int nown = (tid < NELEM) ? ((NELEM - 1 - tid) / NTH + 1) : 0;
    alive = (nown >= 64) ? ~0ull : ((1ull << nown) - 1ull);
    if (tid == 0) { ctrl[0] = NSEL; ctrl[3] = 0; }
    int wid = tid >> 6, lane = tid & 63;
    __syncthreads();

    for (int p = 7; p >= 0; --p) {
        for (int i = tid; i < 256 * HS; i += NTH) whist[i] = 0u;
        __syncthreads();
        bool useSkip = (p >= 4);
        uint32_t dskip = useSkip ? ((SKIP >> (8 * p - 32)) & 255u) : 0u;
        uint32_t scnt = 0;
        {
            int j = 0;
            for (int i = tid; i < NELEM; i += NTH, ++j) {
                if ((alive >> j) & 1ull) {
                    uint32_t v = vo[i];
                    if (useSkip && v == SKIP) { scnt++; continue; }
                    unsigned long long K =
                        ((unsigned long long)v << 32) | (0xFFFFFFFFu - (uint32_t)i);
                    uint32_t d = (uint32_t)(K >> (8 * p)) & 255u;
                    atomicAdd(&whist[d * HS + wid], 1u);
                }
            }
        }
        if (useSkip) {
            #pragma unroll
            for (int off = 32; off > 0; off >>= 1) {
                uint32_t o = __shfl_down(scnt, off);
                if (lane + off < 64) scnt += o;
            }
            if (lane == 0 && scnt) atomicAdd(&whist[dskip * HS + wid], scnt);
        }
        __syncthreads();
        if (tid < 256) {
            uint32_t s = 0;
            #pragma unroll
            for (int w = 0; w < NW; ++w) s += whist[tid * HS + w];
            tot[tid] = s;
        }
        __syncthreads();
        if (wid == 0) {
            int R = ctrl[0];
            uint4 tt = ((const uint4*)tot)[lane];
            uint32_t t_[4] = {tt.x, tt.y, tt.z, tt.w};
            uint32_t s_[4];
            uint32_t lsum = 0;
            #pragma unroll
            for (int q = 3; q >= 0; --q) { lsum += t_[q]; s_[q] = lsum; }
            uint32_t suf = lsum;
            #pragma unroll
            for (int off = 1; off < 64; off <<= 1) {
                uint32_t o = __shfl_down(suf, off);
                if (lane + off < 64) suf += o;
            }
            uint32_t above = suf - lsum;
            #pragma unroll
            for (int q = 0; q < 4; ++q) {
                uint32_t sInc = above + s_[q];
                uint32_t sAb  = sInc - t_[q];
                if (sInc >= (uint32_t)R && sAb < (uint32_t)R) {
                    int Rb = R - (int)sAb;
                    ctrl[0] = Rb;
                    ctrl[1] = lane * 4 + q;
                    ctrl[2] = (t_[q] == (uint32_t)Rb) ? 1 : 0;
                }
            }
        }
        __syncthreads();
        int bnd  = ctrl[1];
        int done = ctrl[2];
        {
            int j = 0;
            for (int i = tid; i < NELEM; i += NTH, ++j) {
                if ((alive >> j) & 1ull) {
                    unsigned long long K =
                        ((unsigned long long)vo[i] << 32) | (0xFFFFFFFFu - (uint32_t)i);
                    uint32_t d = (uint32_t)(K >> (8 * p)) & 255u;
                    if (d > (uint32_t)bnd || (done && d == (uint32_t)bnd)) {
                        sel |= 1ull << j; alive &= ~(1ull << j);
                    } else if (d < (uint32_t)bnd) {
                        alive &= ~(1ull << j);
                    }
                }
            }
        }
        __syncthreads();
        if (done) break;   // keys distinct -> guaranteed by p==0
    }

    {
        int j = 0;
        for (int i = tid; i < NELEM; i += NTH, ++j) {
            if ((sel >> j) & 1ull) {
                int pos = atomicAdd(&ctrl[3], 1);
                list[pos] = ((unsigned long long)vo[i] << 32) | (0xFFFFFFFFu - (uint32_t)i);
            }
        }
    }
    __syncthreads();
}

// ---------------------------------------------------------------------------
// Kernel 1: softmax + anchor-valid mask + box decode (bit-exact path).
// ---------------------------------------------------------------------------
__global__ __launch_bounds__(256) void k_decode(
    const float* __restrict__ cls, const float* __restrict__ boxd,
    const float* __restrict__ anchors,
    uint32_t* __restrict__ S, float* __restrict__ boxes)
{
    int idx = blockIdx.x * 256 + threadIdx.x;
    if (idx < B_N * FG * 3) {          // pad entries rank below everything
        int row = idx / 3, j = idx - row * 3;
        S[(size_t)row * A_PAD + A_N + j] = 0u;
    }
    if (idx >= B_N * A_N) return;
    int b = idx / A_N, a = idx - b * A_N;
    const float* cl = cls + (size_t)idx * NCLS;

    float r[NCLS];
    #pragma unroll
    for (int i = 0; i < NCLS; ++i) r[i] = cl[i];
    float mx = r[0];
    #pragma unroll
    for (int i = 1; i < NCLS; ++i) mx = fmaxf(mx, r[i]);
    float sum = 0.0f, mfg = 0.0f;
    #pragma unroll
    for (int i = 0; i < NCLS; ++i) {
        float e = expf(r[i] - mx);
        sum += e;
        r[i] = e;
        if (i > 0) mfg = fmaxf(mfg, e);
    }
    float inv = 1.0f / sum;
    int valid = (mfg * inv) > MIN_SCORE;  // strict >

    #pragma unroll
    for (int c = 0; c < FG; ++c) {
        float s = r[c + 1] * inv;
        S[((size_t)b * FG + c) * A_PAD + a] = valid ? ordf(s) : ORD_NEG1;
    }

    const float* an = anchors + (size_t)a * 4;
    const float* bd = boxd + (size_t)idx * 4;
    float aw = an[2], ah = an[3];
    float cx = an[0] + bd[0] * 0.1f * aw;
    float cy = an[1] + bd[1] * 0.1f * ah;
    float w  = aw * expf(bd[2] * 0.2f);
    float h  = ah * expf(bd[3] * 0.2f);
    float x1 = cx - w * 0.5f, y1 = cy - h * 0.5f;
    float x2 = x1 + w,        y2 = y1 + h;
    x1 = fminf(fmaxf(x1, 0.0f), 1.0f);
    y1 = fminf(fmaxf(y1, 0.0f), 1.0f);
    x2 = fminf(fmaxf(x2, 0.0f), 1.0f);
    y2 = fminf(fmaxf(y2, 0.0f), 1.0f);
    float* bo = boxes + (size_t)idx * 4;
    bo[0] = x1; bo[1] = y1; bo[2] = x2; bo[3] = y2;
}

// ---------------------------------------------------------------------------
// Kernel 2: per-(b,c) top-200 (radix select + rank order) FUSED with fast-NMS.
// ---------------------------------------------------------------------------
#define TOPK_NTH 1024
#define TOPK_NW  (TOPK_NTH/64)
#define TOPK_LDS (A_PAD*4 + TOPN*8 + 256*HS*4 + 256*4 + 16)
__global__ __launch_bounds__(TOPK_NTH) void k_topk_nms(
    const uint32_t* __restrict__ S, const float* __restrict__ boxes,
    int* __restrict__ det_idx, uint32_t* __restrict__ flat)
{
    extern __shared__ unsigned char smem[];
    uint32_t* vo = (uint32_t*)smem;
    unsigned long long* list = (unsigned long long*)(smem + A_PAD*4);
    uint32_t* whist = (uint32_t*)(smem + A_PAD*4 + TOPN*8);
    uint32_t* tot   = whist + 256*HS;
    int*      ctrl  = (int*)(tot + 256);
    float* sx1 = (float*)whist;          // NMS scratch aliases whist region
    float* sy1 = sx1 + TOPN;
    float* sx2 = sy1 + TOPN;
    float* sy2 = sx2 + TOPN;
    float* sar = sy2 + TOPN;
    float* ssc = sar + TOPN;
    int*   sid = (int*)(ssc + TOPN);

    int bc = blockIdx.x;                  // b*FG + c
    int b = bc / FG, c = bc - b * FG;
    int tid = threadIdx.x;
    const uint4* row4 = (const uint4*)(S + (size_t)bc * A_PAD);
    for (int i = tid; i < A_PAD/4; i += TOPK_NTH) ((uint4*)vo)[i] = row4[i];
    __syncthreads();

    topk_select<A_PAD, TOPK_NTH, TOPK_NW, TOPN>(vo, whist, tot, list, ctrl, tid, ORD_NEG1);

    if (tid < TOPN) {
        unsigned long long a = list[tid];
        int r = 0;
        for (int s = 0; s < TOPN; ++s) r += (list[s] > a) ? 1 : 0;
        sid[r] = (int)(0xFFFFFFFFu - (uint32_t)a);
        ssc[r] = unordf((uint32_t)(a >> 32));
    }
    __syncthreads();

    if (tid < TOPN) {
        int a = sid[tid];
        float4 bo = *(const float4*)(boxes + ((size_t)b * A_N + a) * 4);
        sx1[tid] = bo.x; sy1[tid] = bo.y; sx2[tid] = bo.z; sy2[tid] = bo.w;
        sar[tid] = (bo.z - bo.x) * (bo.w - bo.y);
    }
    __syncthreads();

    if (tid < TOPN) {
        float x1 = sx1[tid], y1 = sy1[tid], x2 = sx2[tid], y2 = sy2[tid];
        float aj = sar[tid];
        float s = ssc[tid];
        int dvj = (s > -0.5f) ? 1 : 0;    // invalid anchors are exactly -1.0
        bool sup = false;
        for (int i = 0; i < tid; ++i) {
            float iw = fmaxf(fminf(sx2[i], x2) - fmaxf(sx1[i], x1), 0.0f);
            float ih = fmaxf(fminf(sy2[i], y2) - fmaxf(sy1[i], y1), 0.0f);
            float inter = iw * ih;
            float iou = inter / (sar[i] + aj - inter);   // may be NaN (0/0)
            int dvi = (ssc[i] > -0.5f) ? 1 : 0;
            bool bad = dvi ? !(iou <= NMS_T) : isnan(iou);
            if (bad) sup = true;
        }
        bool keep = dvj && !sup;
        det_idx[bc * TOPN + tid] = sid[tid];
        flat[(size_t)b * FLATN + c * TOPN + tid] = keep ? ordf(s) : ORD_NINF;
    }
}

// ---------------------------------------------------------------------------
// Kernel 3: global top-100 per batch via radix select; rank-indexed epilogue.
// ---------------------------------------------------------------------------
#define T100_NTH 1024
#define T100_NW  (T100_NTH/64)
#define TOP100_LDS (FLATN*4 + MAXOBJ*8 + 256*HS*4 + 256*4 + 16)
__global__ __launch_bounds__(T100_NTH) void k_top100(
    const uint32_t* __restrict__ flat, const int* __restrict__ det_idx,
    const float* __restrict__ boxes,
    float* __restrict__ lab, float* __restrict__ sco, float* __restrict__ va,
    int* __restrict__ sel_anchor, int* __restrict__ sel_valid,
    float* __restrict__ crop)
{
    extern __shared__ unsigned char smem[];
    uint32_t* vo = (uint32_t*)smem;
    unsigned long long* list = (unsigned long long*)(smem + FLATN*4);
    uint32_t* whist = (uint32_t*)(smem + FLATN*4 + MAXOBJ*8);
    uint32_t* tot   = whist + 256*HS;
    int*      ctrl  = (int*)(tot + 256);

    int b = blockIdx.x;
    int tid = threadIdx.x;
    const uint4* f4 = (const uint4*)(flat + (size_t)b * FLATN);
    for (int i = tid; i < FLATN/4; i += T100_NTH) ((uint4*)vo)[i] = f4[i];
    __syncthreads();

    topk_select<FLATN, T100_NTH, T100_NW, MAXOBJ>(vo, whist, tot, list, ctrl, tid, ORD_NINF);

    if (tid < MAXOBJ) {
        unsigned long long K = list[tid];
        int r = 0;
        for (int s = 0; s < MAXOBJ; ++s) r += (list[s] > K) ? 1 : 0;
        int fi = (int)(0xFFFFFFFFu - (uint32_t)K);
        float fv = unordf((uint32_t)(K >> 32));
        int valid = (fv > -1e37f) ? 1 : 0;          // isfinite (scores in (0,1])
        int c = fi / TOPN, t = fi - c * TOPN;
        int anchor = det_idx[((size_t)b * FG + c) * TOPN + t];
        lab[b * MAXOBJ + r] = valid ? (float)c : -1.0f;
        sco[b * MAXOBJ + r] = valid ? fv : 0.0f;
        va [b * MAXOBJ + r] = valid ? 1.0f : 0.0f;
        sel_anchor[b * MAXOBJ + r] = anchor;
        sel_valid [b * MAXOBJ + r] = valid;
        const float* bo = boxes + ((size_t)b * A_N + anchor) * 4;
        float xlo = fminf(bo[0], bo[2]), xhi = fmaxf(bo[0], bo[2]);
        float ylo = fminf(bo[1], bo[3]), yhi = fmaxf(bo[1], bo[3]);
        float* cr = crop + ((size_t)b * MAXOBJ + r) * 4;
        cr[0] = fmaxf(xlo * (float)PROTO_N - 1.0f, 0.0f);
        cr[1] = fminf(xhi * (float)PROTO_N + 1.0f, (float)PROTO_N);
        cr[2] = fmaxf(ylo * (float)PROTO_N - 1.0f, 0.0f);
        cr[3] = fminf(yhi * (float)PROTO_N + 1.0f, (float)PROTO_N);
    }
}

// ---------------------------------------------------------------------------
// Kernel 4: FUSED mask-gen + bilinear x4 upsample + >0.5 threshold.
// Block = (b, n, 68-row output tile). Phase 1: compute <=19 proto-res rows
// (coef dot with wave-uniform SGPR coefs, proto reads coalesced from L2/L3,
// sigmoid, crop) into LDS. Phase 2: upsample tile, float4 stores.
// Invalid objects: straight zero-fill.
// ---------------------------------------------------------------------------
__global__ __launch_bounds__(256) void k_maskresize(
    const float* __restrict__ proto, const float* __restrict__ coefs,
    const int* __restrict__ sel_anchor, const float* __restrict__ crop,
    const int* __restrict__ sel_valid, float* __restrict__ out)
{
    __shared__ float src[19 * PROTO_N];
    int blk = blockIdx.x;            // B*100*8
    int tile = blk & 7;
    int bn = blk >> 3;               // b*100+n
    int b = bn / MAXOBJ;
    int tid = threadIdx.x;

    int oy0 = tile * 68;
    int val = sel_valid[bn];

    if (!val) {                       // block-uniform branch
        float4 z = make_float4(0.f, 0.f, 0.f, 0.f);
        for (int u = tid; u < 68 * PROTO_N; u += 256) {
            int oyl = u / PROTO_N, xq = u - oyl * PROTO_N;
            *(float4*)&out[((size_t)bn * OUT_N + oy0 + oyl) * OUT_N + 4 * xq] = z;
        }
        return;
    }

    float sy0 = (oy0 + 0.5f) * 0.25f - 0.5f;
    float sy1 = (oy0 + 67 + 0.5f) * 0.25f - 0.5f;
    int iy_lo = max((int)floorf(sy0), 0);
    int iy_hi = min((int)floorf(sy1) + 1, PROTO_N - 1);
    int nrows = iy_hi - iy_lo + 1;

    // wave-uniform coef + crop -> scalar registers
    int anchor = __builtin_amdgcn_readfirstlane(sel_anchor[bn]);
    const float* cp = coefs + ((size_t)b * A_N + anchor) * COEF_N;
    float cw[COEF_N];
    #pragma unroll
    for (int i = 0; i < COEF_N; ++i) cw[i] = cp[i];
    const float* cr = crop + (size_t)bn * 4;
    float c0 = cr[0], c1 = cr[1], c2 = cr[2], c3 = cr[3];

    // phase 1: mask rows at proto res -> LDS
    int npx = nrows * PROTO_N;
    for (int p = tid; p < npx; p += 256) {
        int r = p / PROTO_N, x = p - r * PROTO_N;
        int y = iy_lo + r;
        const float4* pr = (const float4*)(proto +
            (((size_t)b * PROTO_N + y) * PROTO_N + x) * COEF_N);
        float d = 0.0f;
        #pragma unroll
        for (int q = 0; q < 8; ++q) {
            float4 v = pr[q];
            d = fmaf(v.x, cw[4*q+0], d);
            d = fmaf(v.y, cw[4*q+1], d);
            d = fmaf(v.z, cw[4*q+2], d);
            d = fmaf(v.w, cw[4*q+3], d);
        }
        float m = 1.0f / (1.0f + __expf(-d));
        float xf = (float)x, yf = (float)y;
        bool keep = (xf >= c0) && (xf < c1) && (yf >= c2) && (yf < c3);
        src[p] = keep ? m : 0.0f;
    }
    __syncthreads();

    // phase 2: x4 bilinear upsample (half-pixel, clamped taps) + >0.5
    const int QPR = PROTO_N;             // 136 output x-quads per row
    const int UNITS = 68 * QPR;          // 9248
    for (int u = tid; u < UNITS; u += 256) {
        int oyl = u / QPR, xq = u - oyl * QPR;
        int oy = oy0 + oyl;
        float sy = (oy + 0.5f) * 0.25f - 0.5f;
        int iy0 = (int)floorf(sy);
        float fy = sy - (float)iy0;
        const float* r0 = src + (min(max(iy0,     0), PROTO_N - 1) - iy_lo) * PROTO_N;
        const float* r1 = src + (min(max(iy0 + 1, 0), PROTO_N - 1) - iy_lo) * PROTO_N;
        int km = (xq == 0) ? 0 : xq - 1;
        int kp = (xq == PROTO_N - 1) ? PROTO_N - 1 : xq + 1;
        float a0 = r0[km], b0 = r0[xq], cc0 = r0[kp];
        float a1 = r1[km], b1 = r1[xq], cc1 = r1[kp];
        float h00 = a0 * 0.375f + b0 * 0.625f;
        float h01 = a0 * 0.125f + b0 * 0.875f;
        float h02 = b0 * 0.875f + cc0 * 0.125f;
        float h03 = b0 * 0.625f + cc0 * 0.375f;
        float h10 = a1 * 0.375f + b1 * 0.625f;
        float h11 = a1 * 0.125f + b1 * 0.875f;
        float h12 = b1 * 0.875f + cc1 * 0.125f;
        float h13 = b1 * 0.625f + cc1 * 0.375f;
        float g = 1.0f - fy;
        float m0 = h00 * g + h10 * fy;
        float m1 = h01 * g + h11 * fy;
        float m2 = h02 * g + h12 * fy;
        float m3 = h03 * g + h13 * fy;
        float4 o;
        o.x = (m0 > 0.5f) ? 1.0f : 0.0f;
        o.y = (m1 > 0.5f) ? 1.0f : 0.0f;
        o.z = (m2 > 0.5f) ? 1.0f : 0.0f;
        o.w = (m3 > 0.5f) ? 1.0f : 0.0f;
        *(float4*)&out[((size_t)bn * OUT_N + oy) * OUT_N + 4 * xq] = o;
    }
}

// ---------------------------------------------------------------------------
extern "C" void kernel_launch(void* const* d_in, const int* in_sizes, int n_in,
                              void* d_out, int out_size, void* d_ws, size_t ws_size,
                              hipStream_t stream)
{
    const float* cls   = (const float*)d_in[0];
    const float* boxd  = (const float*)d_in[1];
    const float* coef  = (const float*)d_in[2];
    const float* proto = (const float*)d_in[3];
    const float* anch  = (const float*)d_in[4];
    float* out = (float*)d_out;

    char* ws = (char*)d_ws;
    size_t off = 0;
    auto alloc = [&](size_t bytes) -> void* {
        void* p = ws + off;
        off += (bytes + 255) & ~(size_t)255;
        return p;
    };
    uint32_t* S      = (uint32_t*)alloc((size_t)B_N * FG * A_PAD * 4);
    float* boxes     = (float*)alloc((size_t)B_N * A_N * 4 * 4);
    int*   det_idx   = (int*)  alloc((size_t)B_N * FG * TOPN * 4);
    uint32_t* flat   = (uint32_t*)alloc((size_t)B_N * FLATN * 4);
    int*   sel_anchor= (int*)  alloc((size_t)B_N * MAXOBJ * 4);
    int*   sel_valid = (int*)  alloc((size_t)B_N * MAXOBJ * 4);
    float* crop      = (float*)alloc((size_t)B_N * MAXOBJ * 4 * 4);
    (void)ws_size; (void)in_sizes; (void)n_in; (void)out_size;

    float* lab = out + MASK_ELEMS;
    float* sco = lab + B_N * MAXOBJ;
    float* va  = sco + B_N * MAXOBJ;

    k_decode<<<(B_N * A_N + 255) / 256, 256, 0, stream>>>(cls, boxd, anch, S, boxes);
    k_topk_nms<<<B_N * FG, TOPK_NTH, TOPK_LDS, stream>>>(S, boxes, det_idx, flat);
    k_top100<<<B_N, T100_NTH, TOP100_LDS, stream>>>(flat, det_idx, boxes, lab, sco, va,
                                                    sel_anchor, sel_valid, crop);
    k_maskresize<<<B_N * MAXOBJ * 8, 256, 0, stream>>>(
        proto, coef, sel_anchor, crop, sel_valid, out);
}

// Round 7
// 177.402 us; speedup vs baseline: 7.4573x; 1.1063x over previous
//
#include <hip/hip_runtime.h>
#include <math.h>

#define A_N     18525
#define A_PAD   18528          // padded row stride (uint4-aligned)
#define B_N     2
#define NCLS    81
#define FG      80
#define TOPN    200
#define MAXOBJ  100
#define PROTO_N 136
#define OUT_N   544
#define COEF_N  32
#define FLATN   (FG*TOPN)      // 16000
#define MIN_SCORE 0.05f
#define NMS_T   0.5f
#define MASK_ELEMS ((size_t)B_N*MAXOBJ*OUT_N*OUT_N)  // 59,187,200

#define ORD_NEG1 0x407FFFFFu   // ordf(-1.0f)
#define ORD_NINF 0x007FFFFFu   // ordf(-inf)
#define HS 17                  // whist stride (16 waves + 1, bank-friendly)

typedef float v4f __attribute__((ext_vector_type(4)));

// monotone float<->uint order map (no NaNs in our data)
__device__ __forceinline__ uint32_t ordf(float x) {
    uint32_t u = __float_as_uint(x);
    return (u & 0x80000000u) ? ~u : (u | 0x80000000u);
}
__device__ __forceinline__ float unordf(uint32_t u) {
    return (u & 0x80000000u) ? __uint_as_float(u & 0x7FFFFFFFu)
                             : __uint_as_float(~u);
}

// ---------------------------------------------------------------------------
// Exact top-NSEL select over NELEM ordered-uint values (round-3 design).
// Result: list[0..NSEL) filled with selected keys in ARBITRARY order.
// ---------------------------------------------------------------------------
template<int NELEM, int NTH, int NW, int NSEL>
__device__ void topk_select(const uint32_t* __restrict__ vo, uint32_t* whist,
                            uint32_t* tot, unsigned long long* list, int* ctrl,
                            int tid, uint32_t SKIP)
{
    unsigned long long alive, sel = 0ull;
    int nown = (tid < NELEM) ? ((NELEM - 1 - tid) / NTH + 1) : 0;
    alive = (nown >= 64) ? ~0ull : ((1ull << nown) - 1ull);
    if (tid == 0) { ctrl[0] = NSEL; ctrl[3] = 0; }
    int wid = tid >> 6, lane = tid & 63;
    __syncthreads();

    for (int p = 7; p >= 0; --p) {
        for (int i = tid; i < 256 * HS; i += NTH) whist[i] = 0u;
        __syncthreads();
        bool useSkip = (p >= 4);
        uint32_t dskip = useSkip ? ((SKIP >> (8 * p - 32)) & 255u) : 0u;
        uint32_t scnt = 0;
        {
            int j = 0;
            for (int i = tid; i < NELEM; i += NTH, ++j) {
                if ((alive >> j) & 1ull) {
                    uint32_t v = vo[i];
                    if (useSkip && v == SKIP) { scnt++; continue; }
                    unsigned long long K =
                        ((unsigned long long)v << 32) | (0xFFFFFFFFu - (uint32_t)i);
                    uint32_t d = (uint32_t)(K >> (8 * p)) & 255u;
                    atomicAdd(&whist[d * HS + wid], 1u);
                }
            }
        }
        if (useSkip) {
            #pragma unroll
            for (int off = 32; off > 0; off >>= 1) {
                uint32_t o = __shfl_down(scnt, off);
                if (lane + off < 64) scnt += o;
            }
            if (lane == 0 && scnt) atomicAdd(&whist[dskip * HS + wid], scnt);
        }
        __syncthreads();
        if (tid < 256) {
            uint32_t s = 0;
            #pragma unroll
            for (int w = 0; w < NW; ++w) s += whist[tid * HS + w];
            tot[tid] = s;
        }
        __syncthreads();
        if (wid == 0) {
            int R = ctrl[0];
            uint4 tt = ((const uint4*)tot)[lane];
            uint32_t t_[4] = {tt.x, tt.y, tt.z, tt.w};
            uint32_t s_[4];
            uint32_t lsum = 0;
            #pragma unroll
            for (int q = 3; q >= 0; --q) { lsum += t_[q]; s_[q] = lsum; }
            uint32_t suf = lsum;
            #pragma unroll
            for (int off = 1; off < 64; off <<= 1) {
                uint32_t o = __shfl_down(suf, off);
                if (lane + off < 64) suf += o;
            }
            uint32_t above = suf - lsum;
            #pragma unroll
            for (int q = 0; q < 4; ++q) {
                uint32_t sInc = above + s_[q];
                uint32_t sAb  = sInc - t_[q];
                if (sInc >= (uint32_t)R && sAb < (uint32_t)R) {
                    int Rb = R - (int)sAb;
                    ctrl[0] = Rb;
                    ctrl[1] = lane * 4 + q;
                    ctrl[2] = (t_[q] == (uint32_t)Rb) ? 1 : 0;
                }
            }
        }
        __syncthreads();
        int bnd  = ctrl[1];
        int done = ctrl[2];
        {
            int j = 0;
            for (int i = tid; i < NELEM; i += NTH, ++j) {
                if ((alive >> j) & 1ull) {
                    unsigned long long K =
                        ((unsigned long long)vo[i] << 32) | (0xFFFFFFFFu - (uint32_t)i);
                    uint32_t d = (uint32_t)(K >> (8 * p)) & 255u;
                    if (d > (uint32_t)bnd || (done && d == (uint32_t)bnd)) {
                        sel |= 1ull << j; alive &= ~(1ull << j);
                    } else if (d < (uint32_t)bnd) {
                        alive &= ~(1ull << j);
                    }
                }
            }
        }
        __syncthreads();
        if (done) break;   // keys distinct -> guaranteed by p==0
    }

    {
        int j = 0;
        for (int i = tid; i < NELEM; i += NTH, ++j) {
            if ((sel >> j) & 1ull) {
                int pos = atomicAdd(&ctrl[3], 1);
                list[pos] = ((unsigned long long)vo[i] << 32) | (0xFFFFFFFFu - (uint32_t)i);
            }
        }
    }
    __syncthreads();
}

// ---------------------------------------------------------------------------
// Kernel 1: softmax + anchor-valid mask + box decode (bit-exact path).
// ---------------------------------------------------------------------------
__global__ __launch_bounds__(256) void k_decode(
    const float* __restrict__ cls, const float* __restrict__ boxd,
    const float* __restrict__ anchors,
    uint32_t* __restrict__ S, float* __restrict__ boxes)
{
    int idx = blockIdx.x * 256 + threadIdx.x;
    if (idx < B_N * FG * 3) {          // pad entries rank below everything
        int row = idx / 3, j = idx - row * 3;
        S[(size_t)row * A_PAD + A_N + j] = 0u;
    }
    if (idx >= B_N * A_N) return;
    int b = idx / A_N, a = idx - b * A_N;
    const float* cl = cls + (size_t)idx * NCLS;

    float r[NCLS];
    #pragma unroll
    for (int i = 0; i < NCLS; ++i) r[i] = cl[i];
    float mx = r[0];
    #pragma unroll
    for (int i = 1; i < NCLS; ++i) mx = fmaxf(mx, r[i]);
    float sum = 0.0f, mfg = 0.0f;
    #pragma unroll
    for (int i = 0; i < NCLS; ++i) {
        float e = expf(r[i] - mx);
        sum += e;
        r[i] = e;
        if (i > 0) mfg = fmaxf(mfg, e);
    }
    float inv = 1.0f / sum;
    int valid = (mfg * inv) > MIN_SCORE;  // strict >

    #pragma unroll
    for (int c = 0; c < FG; ++c) {
        float s = r[c + 1] * inv;
        S[((size_t)b * FG + c) * A_PAD + a] = valid ? ordf(s) : ORD_NEG1;
    }

    const float* an = anchors + (size_t)a * 4;
    const float* bd = boxd + (size_t)idx * 4;
    float aw = an[2], ah = an[3];
    float cx = an[0] + bd[0] * 0.1f * aw;
    float cy = an[1] + bd[1] * 0.1f * ah;
    float w  = aw * expf(bd[2] * 0.2f);
    float h  = ah * expf(bd[3] * 0.2f);
    float x1 = cx - w * 0.5f, y1 = cy - h * 0.5f;
    float x2 = x1 + w,        y2 = y1 + h;
    x1 = fminf(fmaxf(x1, 0.0f), 1.0f);
    y1 = fminf(fmaxf(y1, 0.0f), 1.0f);
    x2 = fminf(fmaxf(x2, 0.0f), 1.0f);
    y2 = fminf(fmaxf(y2, 0.0f), 1.0f);
    float* bo = boxes + (size_t)idx * 4;
    bo[0] = x1; bo[1] = y1; bo[2] = x2; bo[3] = y2;
}

// ---------------------------------------------------------------------------
// Kernel 2: per-(b,c) top-200 (radix select + rank order) FUSED with fast-NMS.
// NMS is cell-parallel: all 1024 threads sweep the 200x200 (i<j) grid and
// set sup[j] on any bad pair (same-value races benign) — OR semantics
// identical to the reference's column max.
// ---------------------------------------------------------------------------
#define TOPK_NTH 1024
#define TOPK_NW  (TOPK_NTH/64)
#define TOPK_LDS (A_PAD*4 + TOPN*8 + 256*HS*4 + 256*4 + 16)
__global__ __launch_bounds__(TOPK_NTH) void k_topk_nms(
    const uint32_t* __restrict__ S, const float* __restrict__ boxes,
    int* __restrict__ det_idx, uint32_t* __restrict__ flat)
{
    extern __shared__ unsigned char smem[];
    uint32_t* vo = (uint32_t*)smem;
    unsigned long long* list = (unsigned long long*)(smem + A_PAD*4);
    uint32_t* whist = (uint32_t*)(smem + A_PAD*4 + TOPN*8);
    uint32_t* tot   = whist + 256*HS;
    int*      ctrl  = (int*)(tot + 256);
    float* sx1 = (float*)whist;          // NMS scratch aliases whist region
    float* sy1 = sx1 + TOPN;
    float* sx2 = sy1 + TOPN;
    float* sy2 = sx2 + TOPN;
    float* sar = sy2 + TOPN;
    float* ssc = sar + TOPN;
    int*   sid = (int*)(ssc + TOPN);
    int*   sup = sid + TOPN;

    int bc = blockIdx.x;                  // b*FG + c
    int b = bc / FG, c = bc - b * FG;
    int tid = threadIdx.x;
    const uint4* row4 = (const uint4*)(S + (size_t)bc * A_PAD);
    for (int i = tid; i < A_PAD/4; i += TOPK_NTH) ((uint4*)vo)[i] = row4[i];
    __syncthreads();

    topk_select<A_PAD, TOPK_NTH, TOPK_NW, TOPN>(vo, whist, tot, list, ctrl, tid, ORD_NEG1);

    if (tid < TOPN) {
        unsigned long long a = list[tid];
        int r = 0;
        for (int s = 0; s < TOPN; ++s) r += (list[s] > a) ? 1 : 0;
        sid[r] = (int)(0xFFFFFFFFu - (uint32_t)a);
        ssc[r] = unordf((uint32_t)(a >> 32));
    }
    __syncthreads();

    if (tid < TOPN) {
        int a = sid[tid];
        float4 bo = *(const float4*)(boxes + ((size_t)b * A_N + a) * 4);
        sx1[tid] = bo.x; sy1[tid] = bo.y; sx2[tid] = bo.z; sy2[tid] = bo.w;
        sar[tid] = (bo.z - bo.x) * (bo.w - bo.y);
        sup[tid] = 0;
    }
    __syncthreads();

    // cell-parallel NMS: cells of the 200x200 grid, only i<j computed
    for (int cell = tid; cell < TOPN * TOPN; cell += TOPK_NTH) {
        int j = cell / TOPN, i = cell - j * TOPN;
        if (i < j) {
            float iw = fmaxf(fminf(sx2[i], sx2[j]) - fmaxf(sx1[i], sx1[j]), 0.0f);
            float ih = fmaxf(fminf(sy2[i], sy2[j]) - fmaxf(sy1[i], sy1[j]), 0.0f);
            float inter = iw * ih;
            float iou = inter / (sar[i] + sar[j] - inter);   // may be NaN (0/0)
            int dvi = (ssc[i] > -0.5f) ? 1 : 0;
            // reference: iou * det_valid[i] (NaN survives *0), keep = max <= T
            bool bad = dvi ? !(iou <= NMS_T) : isnan(iou);
            if (bad) sup[j] = 1;
        }
    }
    __syncthreads();

    if (tid < TOPN) {
        float s = ssc[tid];
        int dvj = (s > -0.5f) ? 1 : 0;    // invalid anchors are exactly -1.0
        bool keep = dvj && !sup[tid];
        det_idx[bc * TOPN + tid] = sid[tid];
        flat[(size_t)b * FLATN + c * TOPN + tid] = keep ? ordf(s) : ORD_NINF;
    }
}

// ---------------------------------------------------------------------------
// Kernel 3: global top-100 per batch via radix select; rank-indexed epilogue.
// ---------------------------------------------------------------------------
#define T100_NTH 1024
#define T100_NW  (T100_NTH/64)
#define TOP100_LDS (FLATN*4 + MAXOBJ*8 + 256*HS*4 + 256*4 + 16)
__global__ __launch_bounds__(T100_NTH) void k_top100(
    const uint32_t* __restrict__ flat, const int* __restrict__ det_idx,
    const float* __restrict__ boxes,
    float* __restrict__ lab, float* __restrict__ sco, float* __restrict__ va,
    int* __restrict__ sel_anchor, int* __restrict__ sel_valid,
    float* __restrict__ crop)
{
    extern __shared__ unsigned char smem[];
    uint32_t* vo = (uint32_t*)smem;
    unsigned long long* list = (unsigned long long*)(smem + FLATN*4);
    uint32_t* whist = (uint32_t*)(smem + FLATN*4 + MAXOBJ*8);
    uint32_t* tot   = whist + 256*HS;
    int*      ctrl  = (int*)(tot + 256);

    int b = blockIdx.x;
    int tid = threadIdx.x;
    const uint4* f4 = (const uint4*)(flat + (size_t)b * FLATN);
    for (int i = tid; i < FLATN/4; i += T100_NTH) ((uint4*)vo)[i] = f4[i];
    __syncthreads();

    topk_select<FLATN, T100_NTH, T100_NW, MAXOBJ>(vo, whist, tot, list, ctrl, tid, ORD_NINF);

    if (tid < MAXOBJ) {
        unsigned long long K = list[tid];
        int r = 0;
        for (int s = 0; s < MAXOBJ; ++s) r += (list[s] > K) ? 1 : 0;
        int fi = (int)(0xFFFFFFFFu - (uint32_t)K);
        float fv = unordf((uint32_t)(K >> 32));
        int valid = (fv > -1e37f) ? 1 : 0;          // isfinite (scores in (0,1])
        int c = fi / TOPN, t = fi - c * TOPN;
        int anchor = det_idx[((size_t)b * FG + c) * TOPN + t];
        lab[b * MAXOBJ + r] = valid ? (float)c : -1.0f;
        sco[b * MAXOBJ + r] = valid ? fv : 0.0f;
        va [b * MAXOBJ + r] = valid ? 1.0f : 0.0f;
        sel_anchor[b * MAXOBJ + r] = anchor;
        sel_valid [b * MAXOBJ + r] = valid;
        const float* bo = boxes + ((size_t)b * A_N + anchor) * 4;
        float xlo = fminf(bo[0], bo[2]), xhi = fmaxf(bo[0], bo[2]);
        float ylo = fminf(bo[1], bo[3]), yhi = fmaxf(bo[1], bo[3]);
        float* cr = crop + ((size_t)b * MAXOBJ + r) * 4;
        cr[0] = fmaxf(xlo * (float)PROTO_N - 1.0f, 0.0f);
        cr[1] = fminf(xhi * (float)PROTO_N + 1.0f, (float)PROTO_N);
        cr[2] = fmaxf(ylo * (float)PROTO_N - 1.0f, 0.0f);
        cr[3] = fminf(yhi * (float)PROTO_N + 1.0f, (float)PROTO_N);
    }
}

// ---------------------------------------------------------------------------
// Kernel 4: FUSED mask-gen + bilinear x4 upsample + >0.5 threshold.
// Non-temporal float4 stores (write-once streaming output; keep L2 for proto).
// ---------------------------------------------------------------------------
__global__ __launch_bounds__(256) void k_maskresize(
    const float* __restrict__ proto, const float* __restrict__ coefs,
    const int* __restrict__ sel_anchor, const float* __restrict__ crop,
    const int* __restrict__ sel_valid, float* __restrict__ out)
{
    __shared__ float src[19 * PROTO_N];
    int blk = blockIdx.x;            // B*100*8
    int tile = blk & 7;
    int bn = blk >> 3;               // b*100+n
    int b = bn / MAXOBJ;
    int tid = threadIdx.x;

    int oy0 = tile * 68;
    int val = sel_valid[bn];

    if (!val) {                       // block-uniform branch
        v4f z = {0.f, 0.f, 0.f, 0.f};
        for (int u = tid; u < 68 * PROTO_N; u += 256) {
            int oyl = u / PROTO_N, xq = u - oyl * PROTO_N;
            __builtin_nontemporal_store(z,
                (v4f*)&out[((size_t)bn * OUT_N + oy0 + oyl) * OUT_N + 4 * xq]);
        }
        return;
    }

    float sy0 = (oy0 + 0.5f) * 0.25f - 0.5f;
    float sy1 = (oy0 + 67 + 0.5f) * 0.25f - 0.5f;
    int iy_lo = max((int)floorf(sy0), 0);
    int iy_hi = min((int)floorf(sy1) + 1, PROTO_N - 1);
    int nrows = iy_hi - iy_lo + 1;

    // wave-uniform coef + crop -> scalar registers
    int anchor = __builtin_amdgcn_readfirstlane(sel_anchor[bn]);
    const float* cp = coefs + ((size_t)b * A_N + anchor) * COEF_N;
    float cw[COEF_N];
    #pragma unroll
    for (int i = 0; i < COEF_N; ++i) cw[i] = cp[i];
    const float* cr = crop + (size_t)bn * 4;
    float c0 = cr[0], c1 = cr[1], c2 = cr[2], c3 = cr[3];

    // phase 1: mask rows at proto res -> LDS
    int npx = nrows * PROTO_N;
    for (int p = tid; p < npx; p += 256) {
        int r = p / PROTO_N, x = p - r * PROTO_N;
        int y = iy_lo + r;
        const float4* pr = (const float4*)(proto +
            (((size_t)b * PROTO_N + y) * PROTO_N + x) * COEF_N);
        float d = 0.0f;
        #pragma unroll
        for (int q = 0; q < 8; ++q) {
            float4 v = pr[q];
            d = fmaf(v.x, cw[4*q+0], d);
            d = fmaf(v.y, cw[4*q+1], d);
            d = fmaf(v.z, cw[4*q+2], d);
            d = fmaf(v.w, cw[4*q+3], d);
        }
        float m = 1.0f / (1.0f + __expf(-d));
        float xf = (float)x, yf = (float)y;
        bool keep = (xf >= c0) && (xf < c1) && (yf >= c2) && (yf < c3);
        src[p] = keep ? m : 0.0f;
    }
    __syncthreads();

    // phase 2: x4 bilinear upsample (half-pixel, clamped taps) + >0.5
    const int QPR = PROTO_N;             // 136 output x-quads per row
    const int UNITS = 68 * QPR;          // 9248
    for (int u = tid; u < UNITS; u += 256) {
        int oyl = u / QPR, xq = u - oyl * QPR;
        int oy = oy0 + oyl;
        float sy = (oy + 0.5f) * 0.25f - 0.5f;
        int iy0 = (int)floorf(sy);
        float fy = sy - (float)iy0;
        const float* r0 = src + (min(max(iy0,     0), PROTO_N - 1) - iy_lo) * PROTO_N;
        const float* r1 = src + (min(max(iy0 + 1, 0), PROTO_N - 1) - iy_lo) * PROTO_N;
        int km = (xq == 0) ? 0 : xq - 1;
        int kp = (xq == PROTO_N - 1) ? PROTO_N - 1 : xq + 1;
        float a0 = r0[km], b0 = r0[xq], cc0 = r0[kp];
        float a1 = r1[km], b1 = r1[xq], cc1 = r1[kp];
        float h00 = a0 * 0.375f + b0 * 0.625f;
        float h01 = a0 * 0.125f + b0 * 0.875f;
        float h02 = b0 * 0.875f + cc0 * 0.125f;
        float h03 = b0 * 0.625f + cc0 * 0.375f;
        float h10 = a1 * 0.375f + b1 * 0.625f;
        float h11 = a1 * 0.125f + b1 * 0.875f;
        float h12 = b1 * 0.875f + cc1 * 0.125f;
        float h13 = b1 * 0.625f + cc1 * 0.375f;
        float g = 1.0f - fy;
        float m0 = h00 * g + h10 * fy;
        float m1 = h01 * g + h11 * fy;
        float m2 = h02 * g + h12 * fy;
        float m3 = h03 * g + h13 * fy;
        v4f o;
        o.x = (m0 > 0.5f) ? 1.0f : 0.0f;
        o.y = (m1 > 0.5f) ? 1.0f : 0.0f;
        o.z = (m2 > 0.5f) ? 1.0f : 0.0f;
        o.w = (m3 > 0.5f) ? 1.0f : 0.0f;
        __builtin_nontemporal_store(o,
            (v4f*)&out[((size_t)bn * OUT_N + oy) * OUT_N + 4 * xq]);
    }
}

// ---------------------------------------------------------------------------
extern "C" void kernel_launch(void* const* d_in, const int* in_sizes, int n_in,
                              void* d_out, int out_size, void* d_ws, size_t ws_size,
                              hipStream_t stream)
{
    const float* cls   = (const float*)d_in[0];
    const float* boxd  = (const float*)d_in[1];
    const float* coef  = (const float*)d_in[2];
    const float* proto = (const float*)d_in[3];
    const float* anch  = (const float*)d_in[4];
    float* out = (float*)d_out;

    char* ws = (char*)d_ws;
    size_t off = 0;
    auto alloc = [&](size_t bytes) -> void* {
        void* p = ws + off;
        off += (bytes + 255) & ~(size_t)255;
        return p;
    };
    uint32_t* S      = (uint32_t*)alloc((size_t)B_N * FG * A_PAD * 4);
    float* boxes     = (float*)alloc((size_t)B_N * A_N * 4 * 4);
    int*   det_idx   = (int*)  alloc((size_t)B_N * FG * TOPN * 4);
    uint32_t* flat   = (uint32_t*)alloc((size_t)B_N * FLATN * 4);
    int*   sel_anchor= (int*)  alloc((size_t)B_N * MAXOBJ * 4);
    int*   sel_valid = (int*)  alloc((size_t)B_N * MAXOBJ * 4);
    float* crop      = (float*)alloc((size_t)B_N * MAXOBJ * 4 * 4);
    (void)ws_size; (void)in_sizes; (void)n_in; (void)out_size;

    float* lab = out + MASK_ELEMS;
    float* sco = lab + B_N * MAXOBJ;
    float* va  = sco + B_N * MAXOBJ;

    k_decode<<<(B_N * A_N + 255) / 256, 256, 0, stream>>>(cls, boxd, anch, S, boxes);
    k_topk_nms<<<B_N * FG, TOPK_NTH, TOPK_LDS, stream>>>(S, boxes, det_idx, flat);
    k_top100<<<B_N, T100_NTH, TOP100_LDS, stream>>>(flat, det_idx, boxes, lab, sco, va,
                                                    sel_anchor, sel_valid, crop);
    k_maskresize<<<B_N * MAXOBJ * 8, 256, 0, stream>>>(
        proto, coef, sel_anchor, crop, sel_valid, out);
}